// Round 3
// baseline (758.634 us; speedup 1.0000x reference)
//
#include <hip/hip_runtime.h>
#include <cstdint>

typedef unsigned short u16;
typedef __bf16 bf16_t;
typedef bf16_t bf16x8 __attribute__((ext_vector_type(8)));
typedef float f32x4 __attribute__((ext_vector_type(4)));

#define B_ 4
#define S_ 1024
#define D_ 1024
#define E_ 8
#define R_ 8
#define H_ 16
#define DH_ 64

// direct global -> LDS, 16B per lane (dest must be wave-uniform base + lane*16)
#define GLOAD16(gp, lp) __builtin_amdgcn_global_load_lds( \
        (const __attribute__((address_space(1))) void*)(gp), \
        (__attribute__((address_space(3))) void*)(lp), 16, 0, 0)

static __device__ __forceinline__ u16 f2b(float f){
    union { float f; uint32_t i; } v; v.f = f;
    uint32_t i = v.i;
    uint32_t r = i + 0x7FFFu + ((i >> 16) & 1u);   // RNE
    return (u16)(r >> 16);
}

// ---------------- fp32 -> bf16 convert (vectorized, n % 4 == 0) ----------------
__global__ void k_cvt4(const float4* src, ushort4* dst, int n4){
    for (int i = blockIdx.x*blockDim.x + threadIdx.x; i < n4; i += gridDim.x*blockDim.x){
        float4 v = src[i];
        ushort4 o;
        o.x = f2b(v.x); o.y = f2b(v.y); o.z = f2b(v.z); o.w = f2b(v.w);
        dst[i] = o;
    }
}

// fused convert of the four LoRA B matrices (each E*D*R = 64K elems)
__global__ void k_cvtB(const float* qB, const float* kB, const float* vB, const float* oB,
                       u16* dst){
    const float* src = (blockIdx.y==0)?qB:(blockIdx.y==1)?kB:(blockIdx.y==2)?vB:oB;
    u16* d = dst + (size_t)blockIdx.y*E_*D_*R_;
    for (int i = blockIdx.x*blockDim.x + threadIdx.x; i < E_*D_*R_; i += gridDim.x*blockDim.x)
        d[i] = f2b(src[i]);
}

// ---------------- router: cw_pool + const term ----------------
__global__ void k_cwp(const float* conv_w, const float* conv_b, const float* pool_w,
                      const float* pool_b, float* cwp, float* constk){
    __shared__ float red[256];
    int bid = blockIdx.x;
    if (bid < 12){
        int j = bid*256 + threadIdx.x;       // j = t*1024 + i
        int t = j >> 10, i = j & 1023;
        float acc = 0.f;
        for (int o = 0; o < D_; ++o)
            acc += pool_w[o] * conv_w[(size_t)o*3072 + i*3 + t];
        cwp[j] = acc;
    } else {
        float acc = 0.f;
        for (int o = threadIdx.x; o < D_; o += 256) acc += pool_w[o] * conv_b[o];
        red[threadIdx.x] = acc; __syncthreads();
        for (int s = 128; s > 0; s >>= 1){
            if (threadIdx.x < s) red[threadIdx.x] += red[threadIdx.x+s];
            __syncthreads();
        }
        if (threadIdx.x == 0) *constk = red[0] + pool_b[0];
    }
}

// ---------------- router: scores[b,s] ----------------
__global__ void k_scores(const float* x, const float* cwp, const float* constk, float* scores){
    int s = blockIdx.x, b = blockIdx.y;
    const float* xb = x + (size_t)b*S_*D_;
    float acc = 0.f;
    for (int j = threadIdx.x; j < 3*D_; j += 256){
        int t = j >> 10, i = j & 1023;
        int sm = s + t - 1;
        if (sm >= 0 && sm < S_) acc += xb[(size_t)sm*D_ + i] * cwp[j];
    }
    __shared__ float red[256];
    red[threadIdx.x] = acc; __syncthreads();
    for (int st = 128; st > 0; st >>= 1){
        if (threadIdx.x < st) red[threadIdx.x] += red[threadIdx.x+st];
        __syncthreads();
    }
    if (threadIdx.x == 0) scores[b*S_ + s] = red[0] + *constk;
}

// ---------------- router: softmax over seq ----------------
__global__ void k_softw(const float* scores, float* wsm){
    int b = blockIdx.x;
    __shared__ float red[256];
    float mx = -1e30f;
    for (int s = threadIdx.x; s < S_; s += 256) mx = fmaxf(mx, scores[b*S_+s]);
    red[threadIdx.x] = mx; __syncthreads();
    for (int st = 128; st > 0; st >>= 1){
        if (threadIdx.x < st) red[threadIdx.x] = fmaxf(red[threadIdx.x], red[threadIdx.x+st]);
        __syncthreads();
    }
    mx = red[0]; __syncthreads();
    float sum = 0.f;
    for (int s = threadIdx.x; s < S_; s += 256) sum += __expf(scores[b*S_+s] - mx);
    red[threadIdx.x] = sum; __syncthreads();
    for (int st = 128; st > 0; st >>= 1){
        if (threadIdx.x < st) red[threadIdx.x] += red[threadIdx.x+st];
        __syncthreads();
    }
    float inv = 1.f / red[0];
    for (int s = threadIdx.x; s < S_; s += 256)
        wsm[b*S_+s] = __expf(scores[b*S_+s] - mx) * inv;
}

// ---------------- router: xw[b][i*3+t] = sum_s w[s] x[b,s+t-1,i] ----------------
// 256 threads: wave w owns sequence quarter [w*256, (w+1)*256); LDS-reduce at end
__global__ void k_xw(const float* x, const float* wsm, float* xwl){
    int b = blockIdx.y;
    int lane = threadIdx.x & 63;
    int w = threadIdx.x >> 6;
    int i = blockIdx.x*64 + lane;
    const float* xb = x + (size_t)b*S_*D_;
    float a0 = 0.f, a1 = 0.f, a2 = 0.f;
    #pragma unroll 4
    for (int r = w*256; r < (w+1)*256; ++r){
        float xv = xb[(size_t)r*D_ + i];
        float w1 = wsm[b*S_ + r];
        float w0 = (r+1 < S_) ? wsm[b*S_ + r + 1] : 0.f;
        float w2 = (r >= 1)   ? wsm[b*S_ + r - 1] : 0.f;
        a0 += w0*xv; a1 += w1*xv; a2 += w2*xv;
    }
    __shared__ float red[3][4][64];
    red[0][w][lane] = a0; red[1][w][lane] = a1; red[2][w][lane] = a2;
    __syncthreads();
    if (w == 0){
        a0 = red[0][0][lane] + red[0][1][lane] + red[0][2][lane] + red[0][3][lane];
        a1 = red[1][0][lane] + red[1][1][lane] + red[1][2][lane] + red[1][3][lane];
        a2 = red[2][0][lane] + red[2][1][lane] + red[2][2][lane] + red[2][3][lane];
        xwl[b*3072 + i*3 + 0] = a0;
        xwl[b*3072 + i*3 + 1] = a1;
        xwl[b*3072 + i*3 + 2] = a2;
    }
}

// ---------------- router: pooled[b,o] ----------------
__global__ void k_pooled(const float* conv_w, const float* conv_b, const float* xwl, float* pooled){
    int o = blockIdx.x*4 + (threadIdx.x >> 6);
    int lane = threadIdx.x & 63;
    const float* cw = conv_w + (size_t)o*3072;
    float a0=0.f, a1=0.f, a2=0.f, a3=0.f;
    for (int j = lane; j < 3072; j += 64){
        float c = cw[j];
        a0 += c*xwl[j]; a1 += c*xwl[3072+j]; a2 += c*xwl[2*3072+j]; a3 += c*xwl[3*3072+j];
    }
    for (int off = 32; off; off >>= 1){
        a0 += __shfl_down(a0, off); a1 += __shfl_down(a1, off);
        a2 += __shfl_down(a2, off); a3 += __shfl_down(a3, off);
    }
    if (lane == 0){
        float cb = conv_b[o];
        pooled[0*D_+o] = a0+cb; pooled[1*D_+o] = a1+cb;
        pooled[2*D_+o] = a2+cb; pooled[3*D_+o] = a3+cb;
    }
}

// ---------------- router: logits + softmax -> route[b,e] ----------------
__global__ void k_route(const float* pooled, const float* rlin_w, const float* rlin_b, float* route){
    __shared__ float lg[B_][E_];
    int t = threadIdx.x;
    int b = t >> 6, e = (t >> 3) & 7, part = t & 7;
    float acc = 0.f;
    for (int o = part; o < D_; o += 8) acc += pooled[b*D_+o] * rlin_w[e*D_+o];
    acc += __shfl_down(acc, 4); acc += __shfl_down(acc, 2); acc += __shfl_down(acc, 1);
    if (part == 0) lg[b][e] = acc + rlin_b[e];
    __syncthreads();
    if (t < B_){
        float mx = -1e30f;
        for (int e2 = 0; e2 < E_; ++e2) mx = fmaxf(mx, lg[t][e2]);
        float ex[E_], sum = 0.f;
        for (int e2 = 0; e2 < E_; ++e2){ ex[e2] = expf(lg[t][e2]-mx); sum += ex[e2]; }
        for (int e2 = 0; e2 < E_; ++e2) route[t*E_+e2] = ex[e2]/sum;
    }
}

// ---------------- AeffT[z][d][k] = 2*route[b,e]*A_p[e,r,d], k=e*8+r ----------------
__global__ void k_aeff(const float* qA, const float* kA, const float* vA, const float* oA,
                       const float* route, u16* AeffT){
    int dc = blockIdx.x, b = blockIdx.y, p = blockIdx.z;
    const float* Ap = (p==0)?qA:(p==1)?kA:(p==2)?vA:oA;
    int z = p*4 + b;
    for (int idx = threadIdx.x; idx < 64*64; idx += 256){
        int dl = idx >> 6, kk = idx & 63;
        int d = dc*64 + dl;
        int e = kk >> 3, r = kk & 7;
        float v = 2.0f * route[b*E_+e] * Ap[(size_t)(e*R_+r)*D_ + d];
        AeffT[((size_t)z*D_ + d)*64 + kk] = f2b(v);
    }
}

// ---------------- Weff[z][n][d] = W_p[n,d] + Bfold[n,:] @ AeffT[:,d]  (K=64 MFMA) ----------------
__global__ __launch_bounds__(256) void k_weff(
        const u16* B16,                       // bf16 copies of q/k/v/o B, each 64K elems
        const float* qW, const float* kW, const float* vW, const float* oW,
        const u16* AeffT, u16* Weff){
    __shared__ __align__(16) u16 As[128*64];
    __shared__ __align__(16) u16 Bs[128*64];
    int z = blockIdx.z, p = z >> 2;
    const u16* Bp = B16 + (size_t)p*E_*D_*R_;
    const float* Wp = (p==0)?qW:(p==1)?kW:(p==2)?vW:oW;
    int n0 = blockIdx.x*128, d0 = blockIdx.y*128;
    int tid = threadIdx.x;
    int e = tid & 7, row = tid >> 3;
    // LDS dest element offset (row+pass*32)*64 + e*8 == pass*2048 + tid*8  ->
    // per-wave uniform base + lane*16B: global_load_lds-compatible
    for (int pass = 0; pass < 4; ++pass){
        int rr = row + pass*32;
        GLOAD16(&Bp[((size_t)e*D_ + (n0+rr))*R_],           &As[pass*2048 + tid*8]);
        GLOAD16(&AeffT[((size_t)z*D_ + (d0+rr))*64 + e*8],  &Bs[pass*2048 + tid*8]);
    }
    __syncthreads();
    int l = tid & 63, w = tid >> 6;
    int wm = (w & 1)*64, wn = (w >> 1)*64;
    int lr = l & 15, quad = l >> 4;
    f32x4 acc[4][4] = {};
    for (int kk = 0; kk < 64; kk += 32){
        bf16x8 af[4], bg[4];
        for (int i = 0; i < 4; ++i) af[i] = *(const bf16x8*)&As[(wm + i*16 + lr)*64 + kk + quad*8];
        for (int j = 0; j < 4; ++j) bg[j] = *(const bf16x8*)&Bs[(wn + j*16 + lr)*64 + kk + quad*8];
        for (int i = 0; i < 4; ++i)
            for (int j = 0; j < 4; ++j)
                acc[i][j] = __builtin_amdgcn_mfma_f32_16x16x32_bf16(af[i], bg[j], acc[i][j], 0, 0, 0);
    }
    u16* Wz = Weff + (size_t)z*D_*D_;
    for (int i = 0; i < 4; ++i)
        for (int j = 0; j < 4; ++j)
            for (int r2 = 0; r2 < 4; ++r2){
                int n = n0 + wm + i*16 + quad*4 + r2;
                int d = d0 + wn + j*16 + lr;
                Wz[(size_t)n*D_ + d] = f2b(acc[i][j][r2] + Wp[(size_t)n*D_ + d]);
            }
}

// ---------------- shared 128x128 MFMA GEMM body (direct-to-LDS staging) ----------------
// C[m,n] = scale*(sum_k A[m,k]*Bw[n,k] + bias[n]);  writes bf16 (Cb) or fp32 (Cf)
static __device__ __forceinline__ void gemm_body(
        const u16* __restrict__ A, int lda,
        const u16* __restrict__ Bw,
        u16* Cb, float* Cf, int ldc,
        const float* bias, float scale, int K,
        int m0, int n0)
{
    __shared__ __align__(16) u16 As[128*32];
    __shared__ __align__(16) u16 Bs[128*32];
    int tid = threadIdx.x;
    int srow = tid >> 2, skc = (tid & 3)*8;
    // LDS dest element offset srow*32+skc == tid*8 -> wave-uniform base + lane*16B
    u16* asd = &As[tid*8];
    u16* bsd = &Bs[tid*8];
    const u16* ga0 = &A [(size_t)(m0+srow)*lda + skc];
    const u16* ga1 = &A [(size_t)(m0+srow+64)*lda + skc];
    const u16* gb0 = &Bw[(size_t)(n0+srow)*D_ + skc];
    const u16* gb1 = &Bw[(size_t)(n0+srow+64)*D_ + skc];
    int l = tid & 63, w = tid >> 6;
    int wm = (w & 1)*64, wn = (w >> 1)*64;
    int lr = l & 15, quad = l >> 4;
    f32x4 acc[4][4] = {};
    for (int k0 = 0; k0 < K; k0 += 32){
        __syncthreads();
        GLOAD16(ga0 + k0, asd);
        GLOAD16(ga1 + k0, asd + 2048);
        GLOAD16(gb0 + k0, bsd);
        GLOAD16(gb1 + k0, bsd + 2048);
        __syncthreads();
        bf16x8 af[4], bg[4];
        for (int i = 0; i < 4; ++i) af[i] = *(const bf16x8*)&As[(wm + i*16 + lr)*32 + quad*8];
        for (int j = 0; j < 4; ++j) bg[j] = *(const bf16x8*)&Bs[(wn + j*16 + lr)*32 + quad*8];
        for (int i = 0; i < 4; ++i)
            for (int j = 0; j < 4; ++j)
                acc[i][j] = __builtin_amdgcn_mfma_f32_16x16x32_bf16(af[i], bg[j], acc[i][j], 0, 0, 0);
    }
    for (int j = 0; j < 4; ++j){
        int n = n0 + wn + j*16 + lr;
        float bv = bias ? bias[n] : 0.f;
        for (int i = 0; i < 4; ++i){
            int mrow = m0 + wm + i*16 + quad*4;
            for (int r2 = 0; r2 < 4; ++r2){
                float val = (acc[i][j][r2] + bv) * scale;
                size_t idx = (size_t)(mrow+r2)*ldc + n;
                if (Cf) __builtin_nontemporal_store(val, &Cf[idx]);
                else    Cb[idx] = f2b(val);
            }
        }
    }
}

// fused q/k/v projection: z in [0,12), p=z>>2 (0=q,1=k,2=v), b=z&3
// qkv buffer laid out [p][b][S][D] -> offset z*S*D (since z = p*4+b)
__global__ __launch_bounds__(256) void k_gemm_qkv(
        const u16* x16, const u16* Weff, u16* qkv, const float* qb, const float* vb){
    int z = blockIdx.z, p = z >> 2, b = z & 3;
    const float* bias = (p==0) ? qb : (p==2) ? vb : (const float*)nullptr;
    float scale = (p==2) ? 1.0f : 0.35355339059327373f;   // 64^-0.25
    gemm_body(x16 + (size_t)b*S_*D_, D_,
              Weff + (size_t)z*D_*D_,
              qkv + (size_t)z*S_*D_, (float*)nullptr, D_,
              bias, scale, 1024, blockIdx.x*128, blockIdx.y*128);
}

// output projection: fp32 result
__global__ __launch_bounds__(256) void k_gemm_o(
        const u16* wv, const u16* WeffO, float* out, const float* ob){
    int b = blockIdx.z;
    gemm_body(wv + (size_t)b*S_*D_, D_,
              WeffO + (size_t)b*D_*D_,
              (u16*)nullptr, out + (size_t)b*S_*D_, D_,
              ob, 1.0f, 1024, blockIdx.x*128, blockIdx.y*128);
}

// ---------------- v -> vT[b][h][d][s] ----------------
__global__ void k_vtrans(const u16* v, u16* vT){
    __shared__ __align__(16) u16 Tl[64*72];
    int st = blockIdx.x, bh = blockIdx.y;
    int b = bh >> 4, h = bh & 15;
    int tid = threadIdx.x;
    int row = tid >> 3, c = (tid & 7)*8;
    const u16* vb = v + (size_t)b*S_*D_ + h*64;
    for (int pass = 0; pass < 2; ++pass){
        int r = row + pass*32;
        *(uint4*)&Tl[r*72 + c] = *(const uint4*)&vb[(size_t)(st*64 + r)*D_ + c];
    }
    __syncthreads();
    u16* vTb = vT + (size_t)bh*64*S_;
    for (int pass = 0; pass < 2; ++pass){
        int dr = row + pass*32;
        union { u16 s[8]; uint4 u; } tmp;
        for (int j = 0; j < 8; ++j) tmp.s[j] = Tl[(c+j)*72 + dr];
        *(uint4*)&vTb[(size_t)dr*S_ + st*64 + c] = tmp.u;
    }
}

// ---------------- fused attention: writes qk (fp32, nontemporal) + wv (bf16) ----------------
__global__ __launch_bounds__(256) void k_attn(const u16* q, const u16* k, const u16* vT,
                                              float* qk_out, u16* wv){
    __shared__ __align__(16) u16 Ql[64*72];
    __shared__ __align__(16) u16 Kl[64*72];
    __shared__ __align__(16) u16 Vt[64*72];
    __shared__ __align__(16) u16 Pl[64*72];
    int qt = blockIdx.x, bh = blockIdx.y;
    int b = bh >> 4, h = bh & 15;
    int q0 = qt*64;
    int tid = threadIdx.x;
    int row = tid >> 3, c = (tid & 7)*8;
    int l = tid & 63, w = tid >> 6;
    int lr = l & 15, quad = l >> 4;
    const u16* qp  = q  + (size_t)b*S_*D_ + h*64;
    const u16* kp  = k  + (size_t)b*S_*D_ + h*64;
    const u16* vTp = vT + (size_t)bh*64*S_;
    float* qko = qk_out + (size_t)bh*S_*S_;
    for (int pass = 0; pass < 2; ++pass){
        int r = row + pass*32;
        *(uint4*)&Ql[r*72 + c] = *(const uint4*)&qp[(size_t)(q0 + r)*D_ + c];
    }
    f32x4 oacc[4] = {};
    float m_i[4], l_i[4];
    for (int r2 = 0; r2 < 4; ++r2){ m_i[r2] = -1e30f; l_i[r2] = 0.f; }
    for (int t0 = 0; t0 < S_; t0 += 64){
        __syncthreads();
        for (int pass = 0; pass < 2; ++pass){
            int r = row + pass*32;
            *(uint4*)&Kl[r*72 + c] = *(const uint4*)&kp[(size_t)(t0 + r)*D_ + c];
            *(uint4*)&Vt[r*72 + c] = *(const uint4*)&vTp[(size_t)r*S_ + t0 + c];
        }
        __syncthreads();
        // S = Q K^T  (wave w: q-rows w*16..w*16+15, all 64 t of this tile)
        f32x4 sacc[4] = {};
        for (int kk = 0; kk < 64; kk += 32){
            bf16x8 aq = *(const bf16x8*)&Ql[(w*16 + lr)*72 + kk + quad*8];
            for (int jn = 0; jn < 4; ++jn){
                bf16x8 bk = *(const bf16x8*)&Kl[(jn*16 + lr)*72 + kk + quad*8];
                sacc[jn] = __builtin_amdgcn_mfma_f32_16x16x32_bf16(aq, bk, sacc[jn], 0, 0, 0);
            }
        }
        // write raw scores (pre-softmax) as fp32 — nontemporal, write-only stream
        for (int jn = 0; jn < 4; ++jn)
            for (int r2 = 0; r2 < 4; ++r2){
                int sq = q0 + w*16 + quad*4 + r2;
                __builtin_nontemporal_store(sacc[jn][r2], &qko[(size_t)sq*S_ + t0 + jn*16 + lr]);
            }
        // online softmax (fp32, from fp32 scores); args to exp are all <= 0
        float alpha[4];
        for (int r2 = 0; r2 < 4; ++r2){
            float mx = fmaxf(fmaxf(sacc[0][r2], sacc[1][r2]), fmaxf(sacc[2][r2], sacc[3][r2]));
            for (int off = 1; off < 16; off <<= 1) mx = fmaxf(mx, __shfl_xor(mx, off));
            float mnew = fmaxf(m_i[r2], mx);
            alpha[r2] = __expf(m_i[r2] - mnew);
            m_i[r2] = mnew;
        }
        f32x4 p[4];
        for (int jn = 0; jn < 4; ++jn)
            for (int r2 = 0; r2 < 4; ++r2)
                p[jn][r2] = __expf(sacc[jn][r2] - m_i[r2]);
        for (int r2 = 0; r2 < 4; ++r2){
            float s = p[0][r2] + p[1][r2] + p[2][r2] + p[3][r2];
            for (int off = 1; off < 16; off <<= 1) s += __shfl_xor(s, off);
            l_i[r2] = l_i[r2]*alpha[r2] + s;
        }
        for (int jn = 0; jn < 4; ++jn)
            for (int r2 = 0; r2 < 4; ++r2)
                oacc[jn][r2] *= alpha[r2];
        // P: C/D layout -> LDS -> A layout
        for (int jn = 0; jn < 4; ++jn)
            for (int r2 = 0; r2 < 4; ++r2)
                Pl[(w*16 + quad*4 + r2)*72 + jn*16 + lr] = f2b(p[jn][r2]);
        __syncthreads();
        // O += P V
        for (int kk = 0; kk < 64; kk += 32){
            bf16x8 ap = *(const bf16x8*)&Pl[(w*16 + lr)*72 + kk + quad*8];
            for (int jn = 0; jn < 4; ++jn){
                bf16x8 bv = *(const bf16x8*)&Vt[(jn*16 + lr)*72 + kk + quad*8];
                oacc[jn] = __builtin_amdgcn_mfma_f32_16x16x32_bf16(ap, bv, oacc[jn], 0, 0, 0);
            }
        }
    }
    u16* wvp = wv + (size_t)b*S_*D_ + h*64;
    for (int r2 = 0; r2 < 4; ++r2){
        float inv = 1.f / l_i[r2];
        int sq = q0 + w*16 + quad*4 + r2;
        for (int jn = 0; jn < 4; ++jn)
            wvp[(size_t)sq*D_ + jn*16 + lr] = f2b(oacc[jn][r2] * inv);
    }
}

extern "C" void kernel_launch(void* const* d_in, const int* in_sizes, int n_in,
                              void* d_out, int out_size, void* d_ws, size_t ws_size,
                              hipStream_t stream){
    const float* x      = (const float*)d_in[0];
    const float* conv_w = (const float*)d_in[1];
    const float* conv_b = (const float*)d_in[2];
    const float* pool_w = (const float*)d_in[3];
    const float* pool_b = (const float*)d_in[4];
    const float* rlin_w = (const float*)d_in[5];
    const float* rlin_b = (const float*)d_in[6];
    const float* qW = (const float*)d_in[7];
    const float* qb = (const float*)d_in[8];
    const float* qA = (const float*)d_in[9];
    const float* qB = (const float*)d_in[10];
    const float* kW = (const float*)d_in[11];
    const float* kA = (const float*)d_in[12];
    const float* kB = (const float*)d_in[13];
    const float* vW = (const float*)d_in[14];
    const float* vb = (const float*)d_in[15];
    const float* vA = (const float*)d_in[16];
    const float* vB = (const float*)d_in[17];
    const float* oW = (const float*)d_in[18];
    const float* ob = (const float*)d_in[19];
    const float* oA = (const float*)d_in[20];
    const float* oB = (const float*)d_in[21];

    char* ws = (char*)d_ws;
    float* route  = (float*)(ws + 0);
    float* scores = (float*)(ws + 1024);
    float* wsm    = (float*)(ws + 20480);
    float* xwl    = (float*)(ws + 40960);
    float* pooled = (float*)(ws + 102400);
    float* cwp    = (float*)(ws + 131072);
    float* constk = (float*)(ws + 143360);
    u16* AeffT = (u16*)(ws + (1ull  << 20));                 // 2 MB
    u16* B16   = (u16*)(ws + (3ull  << 20));                 // 512 KB (q,k,v,o B)
    u16* Weff  = (u16*)(ws + (4ull  << 20));                 // 32 MB
    u16* x16   = (u16*)(ws + (36ull << 20));                 // 8 MB
    u16* qkv   = (u16*)(ws + (44ull << 20));                 // 24 MB: [p][b][S][D], p=0:q 1:k 2:v
    u16* qbuf  = qkv + 0*(size_t)B_*S_*D_;
    u16* kbuf  = qkv + 1*(size_t)B_*S_*D_;
    u16* vbuf  = qkv + 2*(size_t)B_*S_*D_;
    u16* vTbuf = (u16*)(ws + (68ull << 20));                 // 8 MB  -> total 76 MB
    u16* wvbuf = vbuf;                                       // v dead after k_vtrans

    float* out    = (float*)d_out;
    float* qk_out = out + (size_t)B_*S_*D_;

    const long long sDD = (long long)D_*D_;

    // fp32 -> bf16 copies
    k_cvt4<<<2048, 256, 0, stream>>>((const float4*)x, (ushort4*)x16, B_*S_*D_/4);
    k_cvtB<<<dim3(16, 4), 256, 0, stream>>>(qB, kB, vB, oB, B16);

    k_cwp   <<<13, 256, 0, stream>>>(conv_w, conv_b, pool_w, pool_b, cwp, constk);
    k_scores<<<dim3(S_, B_), 256, 0, stream>>>(x, cwp, constk, scores);
    k_softw <<<B_, 256, 0, stream>>>(scores, wsm);
    k_xw    <<<dim3(16, B_), 256, 0, stream>>>(x, wsm, xwl);
    k_pooled<<<256, 256, 0, stream>>>(conv_w, conv_b, xwl, pooled);
    k_route <<<1, 256, 0, stream>>>(pooled, rlin_w, rlin_b, route);
    k_aeff  <<<dim3(16, B_, 4), 256, 0, stream>>>(qA, kA, vA, oA, route, AeffT);
    k_weff  <<<dim3(8, 8, 16), 256, 0, stream>>>(B16, qW, kW, vW, oW, AeffT, Weff);

    // fused q/k/v projections: 768 blocks = 3 blocks/CU
    k_gemm_qkv<<<dim3(8,8,12), 256, 0, stream>>>(x16, Weff, qkv, qb, vb);

    k_vtrans<<<dim3(16, B_*H_), 256, 0, stream>>>(vbuf, vTbuf);
    k_attn  <<<dim3(16, B_*H_), 256, 0, stream>>>(qbuf, kbuf, vTbuf, qk_out, wvbuf);
    k_gemm_o<<<dim3(8,8,B_), 256, 0, stream>>>(wvbuf, Weff + 12*sDD, out, ob);
}

// Round 4
// 684.700 us; speedup vs baseline: 1.1080x; 1.1080x over previous
//
#include <hip/hip_runtime.h>
#include <cstdint>

typedef unsigned short u16;
typedef __bf16 bf16_t;
typedef bf16_t bf16x8 __attribute__((ext_vector_type(8)));
typedef float f32x4 __attribute__((ext_vector_type(4)));

#define B_ 4
#define S_ 1024
#define D_ 1024
#define E_ 8
#define R_ 8
#define H_ 16
#define DH_ 64

// direct global -> LDS, 16B per lane (dest must be wave-uniform base + lane*16)
#define GLOAD16(gp, lp) __builtin_amdgcn_global_load_lds( \
        (const __attribute__((address_space(1))) void*)(gp), \
        (__attribute__((address_space(3))) void*)(lp), 16, 0, 0)

static __device__ __forceinline__ u16 f2b(float f){
    union { float f; uint32_t i; } v; v.f = f;
    uint32_t i = v.i;
    uint32_t r = i + 0x7FFFu + ((i >> 16) & 1u);   // RNE
    return (u16)(r >> 16);
}

// ---------------- fp32 -> bf16 convert (vectorized, n % 4 == 0) ----------------
__global__ void k_cvt4(const float4* src, ushort4* dst, int n4){
    for (int i = blockIdx.x*blockDim.x + threadIdx.x; i < n4; i += gridDim.x*blockDim.x){
        float4 v = src[i];
        ushort4 o;
        o.x = f2b(v.x); o.y = f2b(v.y); o.z = f2b(v.z); o.w = f2b(v.w);
        dst[i] = o;
    }
}

// fused convert of the four LoRA B matrices; block (0,0) also zeroes cwp for k_cwp's atomics
__global__ void k_cvtB(const float* qB, const float* kB, const float* vB, const float* oB,
                       u16* dst, float* cwp){
    const float* src = (blockIdx.y==0)?qB:(blockIdx.y==1)?kB:(blockIdx.y==2)?vB:oB;
    u16* d = dst + (size_t)blockIdx.y*E_*D_*R_;
    for (int i = blockIdx.x*blockDim.x + threadIdx.x; i < E_*D_*R_; i += gridDim.x*blockDim.x)
        d[i] = f2b(src[i]);
    if (blockIdx.x == 0 && blockIdx.y == 0)
        for (int i = threadIdx.x; i < 3*D_; i += blockDim.x) cwp[i] = 0.f;
}

// ---------------- router: cw_pool (atomic partials over o-chunks) + const term ----------------
__global__ void k_cwp(const float* conv_w, const float* conv_b, const float* pool_w,
                      const float* pool_b, float* cwp, float* constk){
    __shared__ float red[256];
    int bid = blockIdx.x, ob = blockIdx.y;
    if (bid < 12){
        int j = bid*256 + threadIdx.x;       // j = t*1024 + i
        int t = j >> 10, i = j & 1023;
        float acc = 0.f;
        for (int o = ob*128; o < (ob+1)*128; ++o)
            acc += pool_w[o] * conv_w[(size_t)o*3072 + i*3 + t];
        atomicAdd(&cwp[j], acc);
    } else if (ob == 0){
        float acc = 0.f;
        for (int o = threadIdx.x; o < D_; o += 256) acc += pool_w[o] * conv_b[o];
        red[threadIdx.x] = acc; __syncthreads();
        for (int s = 128; s > 0; s >>= 1){
            if (threadIdx.x < s) red[threadIdx.x] += red[threadIdx.x+s];
            __syncthreads();
        }
        if (threadIdx.x == 0) *constk = red[0] + pool_b[0];
    }
}

// ---------------- router: h_t[b,s] = cwp_t . x[b,s]  (x read once, coalesced) ----------------
__global__ void k_h(const float* x, const float* cwp, float* h){
    int b = blockIdx.y;
    int w = threadIdx.x >> 6, lane = threadIdx.x & 63;
    int s = blockIdx.x*4 + w;
    const float4* xr = (const float4*)(x + ((size_t)b*S_ + s)*D_);
    const float4* c0 = (const float4*)(cwp);
    const float4* c1 = (const float4*)(cwp + D_);
    const float4* c2 = (const float4*)(cwp + 2*D_);
    float a0 = 0.f, a1 = 0.f, a2 = 0.f;
    #pragma unroll
    for (int it = 0; it < 4; ++it){
        float4 v  = xr[it*64 + lane];
        float4 w0 = c0[it*64 + lane];
        float4 w1 = c1[it*64 + lane];
        float4 w2 = c2[it*64 + lane];
        a0 += v.x*w0.x + v.y*w0.y + v.z*w0.z + v.w*w0.w;
        a1 += v.x*w1.x + v.y*w1.y + v.z*w1.z + v.w*w1.w;
        a2 += v.x*w2.x + v.y*w2.y + v.z*w2.z + v.w*w2.w;
    }
    for (int off = 32; off; off >>= 1){
        a0 += __shfl_down(a0, off);
        a1 += __shfl_down(a1, off);
        a2 += __shfl_down(a2, off);
    }
    if (lane == 0){
        h[(0*B_ + b)*S_ + s] = a0;
        h[(1*B_ + b)*S_ + s] = a1;
        h[(2*B_ + b)*S_ + s] = a2;
    }
}

// ---------------- router: softmax over seq; scores computed inline from h ----------------
__global__ void k_softw(const float* h, const float* constk, float* wsm){
    int b = blockIdx.x;
    const float* h0 = h + (0*B_ + b)*S_;
    const float* h1 = h + (1*B_ + b)*S_;
    const float* h2 = h + (2*B_ + b)*S_;
    float ck = *constk;
    __shared__ float red[256];
    float mx = -1e30f;
    for (int s = threadIdx.x; s < S_; s += 256){
        float v = h1[s] + ck;
        if (s >= 1)     v += h0[s-1];
        if (s+1 < S_)   v += h2[s+1];
        mx = fmaxf(mx, v);
    }
    red[threadIdx.x] = mx; __syncthreads();
    for (int st = 128; st > 0; st >>= 1){
        if (threadIdx.x < st) red[threadIdx.x] = fmaxf(red[threadIdx.x], red[threadIdx.x+st]);
        __syncthreads();
    }
    mx = red[0]; __syncthreads();
    float sum = 0.f;
    for (int s = threadIdx.x; s < S_; s += 256){
        float v = h1[s] + ck;
        if (s >= 1)     v += h0[s-1];
        if (s+1 < S_)   v += h2[s+1];
        sum += __expf(v - mx);
    }
    red[threadIdx.x] = sum; __syncthreads();
    for (int st = 128; st > 0; st >>= 1){
        if (threadIdx.x < st) red[threadIdx.x] += red[threadIdx.x+st];
        __syncthreads();
    }
    float inv = 1.f / red[0];
    for (int s = threadIdx.x; s < S_; s += 256){
        float v = h1[s] + ck;
        if (s >= 1)     v += h0[s-1];
        if (s+1 < S_)   v += h2[s+1];
        wsm[b*S_+s] = __expf(v - mx) * inv;
    }
}

// ---------------- router: xw[b][i*3+t] = sum_s w[s] x[b,s+t-1,i] ----------------
// 256 threads: wave w owns sequence quarter [w*256, (w+1)*256); LDS-reduce at end
__global__ void k_xw(const float* x, const float* wsm, float* xwl){
    int b = blockIdx.y;
    int lane = threadIdx.x & 63;
    int w = threadIdx.x >> 6;
    int i = blockIdx.x*64 + lane;
    const float* xb = x + (size_t)b*S_*D_;
    float a0 = 0.f, a1 = 0.f, a2 = 0.f;
    #pragma unroll 4
    for (int r = w*256; r < (w+1)*256; ++r){
        float xv = xb[(size_t)r*D_ + i];
        float w1 = wsm[b*S_ + r];
        float w0 = (r+1 < S_) ? wsm[b*S_ + r + 1] : 0.f;
        float w2 = (r >= 1)   ? wsm[b*S_ + r - 1] : 0.f;
        a0 += w0*xv; a1 += w1*xv; a2 += w2*xv;
    }
    __shared__ float red[3][4][64];
    red[0][w][lane] = a0; red[1][w][lane] = a1; red[2][w][lane] = a2;
    __syncthreads();
    if (w == 0){
        a0 = red[0][0][lane] + red[0][1][lane] + red[0][2][lane] + red[0][3][lane];
        a1 = red[1][0][lane] + red[1][1][lane] + red[1][2][lane] + red[1][3][lane];
        a2 = red[2][0][lane] + red[2][1][lane] + red[2][2][lane] + red[2][3][lane];
        xwl[b*3072 + i*3 + 0] = a0;
        xwl[b*3072 + i*3 + 1] = a1;
        xwl[b*3072 + i*3 + 2] = a2;
    }
}

// ---------------- router: pooled[b,o] ----------------
__global__ void k_pooled(const float* conv_w, const float* conv_b, const float* xwl, float* pooled){
    int o = blockIdx.x*4 + (threadIdx.x >> 6);
    int lane = threadIdx.x & 63;
    const float* cw = conv_w + (size_t)o*3072;
    float a0=0.f, a1=0.f, a2=0.f, a3=0.f;
    for (int j = lane; j < 3072; j += 64){
        float c = cw[j];
        a0 += c*xwl[j]; a1 += c*xwl[3072+j]; a2 += c*xwl[2*3072+j]; a3 += c*xwl[3*3072+j];
    }
    for (int off = 32; off; off >>= 1){
        a0 += __shfl_down(a0, off); a1 += __shfl_down(a1, off);
        a2 += __shfl_down(a2, off); a3 += __shfl_down(a3, off);
    }
    if (lane == 0){
        float cb = conv_b[o];
        pooled[0*D_+o] = a0+cb; pooled[1*D_+o] = a1+cb;
        pooled[2*D_+o] = a2+cb; pooled[3*D_+o] = a3+cb;
    }
}

// ---------------- router: logits + softmax -> route[b,e] ----------------
__global__ void k_route(const float* pooled, const float* rlin_w, const float* rlin_b, float* route){
    __shared__ float lg[B_][E_];
    int t = threadIdx.x;
    int b = t >> 6, e = (t >> 3) & 7, part = t & 7;
    float acc = 0.f;
    for (int o = part; o < D_; o += 8) acc += pooled[b*D_+o] * rlin_w[e*D_+o];
    acc += __shfl_down(acc, 4); acc += __shfl_down(acc, 2); acc += __shfl_down(acc, 1);
    if (part == 0) lg[b][e] = acc + rlin_b[e];
    __syncthreads();
    if (t < B_){
        float mx = -1e30f;
        for (int e2 = 0; e2 < E_; ++e2) mx = fmaxf(mx, lg[t][e2]);
        float ex[E_], sum = 0.f;
        for (int e2 = 0; e2 < E_; ++e2){ ex[e2] = expf(lg[t][e2]-mx); sum += ex[e2]; }
        for (int e2 = 0; e2 < E_; ++e2) route[t*E_+e2] = ex[e2]/sum;
    }
}

// ---------------- AeffT[z][d][k] = 2*route[b,e]*A_p[e,r,d], k=e*8+r ----------------
__global__ void k_aeff(const float* qA, const float* kA, const float* vA, const float* oA,
                       const float* route, u16* AeffT){
    int dc = blockIdx.x, b = blockIdx.y, p = blockIdx.z;
    const float* Ap = (p==0)?qA:(p==1)?kA:(p==2)?vA:oA;
    int z = p*4 + b;
    for (int idx = threadIdx.x; idx < 64*64; idx += 256){
        int dl = idx >> 6, kk = idx & 63;
        int d = dc*64 + dl;
        int e = kk >> 3, r = kk & 7;
        float v = 2.0f * route[b*E_+e] * Ap[(size_t)(e*R_+r)*D_ + d];
        AeffT[((size_t)z*D_ + d)*64 + kk] = f2b(v);
    }
}

// ---------------- Weff[z][n][d] = W_p[n,d] + Bfold[n,:] @ AeffT[:,d]  (K=64 MFMA) ----------------
__global__ __launch_bounds__(256) void k_weff(
        const u16* B16,                       // bf16 copies of q/k/v/o B, each 64K elems
        const float* qW, const float* kW, const float* vW, const float* oW,
        const u16* AeffT, u16* Weff){
    __shared__ __align__(16) u16 As[128*64];
    __shared__ __align__(16) u16 Bs[128*64];
    int z = blockIdx.z, p = z >> 2;
    const u16* Bp = B16 + (size_t)p*E_*D_*R_;
    const float* Wp = (p==0)?qW:(p==1)?kW:(p==2)?vW:oW;
    int n0 = blockIdx.x*128, d0 = blockIdx.y*128;
    int tid = threadIdx.x;
    int e = tid & 7, row = tid >> 3;
    // LDS dest element offset (row+pass*32)*64 + e*8 == pass*2048 + tid*8  ->
    // per-wave uniform base + lane*16B: global_load_lds-compatible
    for (int pass = 0; pass < 4; ++pass){
        int rr = row + pass*32;
        GLOAD16(&Bp[((size_t)e*D_ + (n0+rr))*R_],           &As[pass*2048 + tid*8]);
        GLOAD16(&AeffT[((size_t)z*D_ + (d0+rr))*64 + e*8],  &Bs[pass*2048 + tid*8]);
    }
    __syncthreads();
    int l = tid & 63, w = tid >> 6;
    int wm = (w & 1)*64, wn = (w >> 1)*64;
    int lr = l & 15, quad = l >> 4;
    f32x4 acc[4][4] = {};
    for (int kk = 0; kk < 64; kk += 32){
        bf16x8 af[4], bg[4];
        for (int i = 0; i < 4; ++i) af[i] = *(const bf16x8*)&As[(wm + i*16 + lr)*64 + kk + quad*8];
        for (int j = 0; j < 4; ++j) bg[j] = *(const bf16x8*)&Bs[(wn + j*16 + lr)*64 + kk + quad*8];
        for (int i = 0; i < 4; ++i)
            for (int j = 0; j < 4; ++j)
                acc[i][j] = __builtin_amdgcn_mfma_f32_16x16x32_bf16(af[i], bg[j], acc[i][j], 0, 0, 0);
    }
    u16* Wz = Weff + (size_t)z*D_*D_;
    for (int i = 0; i < 4; ++i)
        for (int j = 0; j < 4; ++j)
            for (int r2 = 0; r2 < 4; ++r2){
                int n = n0 + wm + i*16 + quad*4 + r2;
                int d = d0 + wn + j*16 + lr;
                Wz[(size_t)n*D_ + d] = f2b(acc[i][j][r2] + Wp[(size_t)n*D_ + d]);
            }
}

// ---------------- shared 128x128 MFMA GEMM body (direct-to-LDS staging) ----------------
// C[m,n] = scale*(sum_k A[m,k]*Bw[n,k] + bias[n]);  writes bf16 (Cb) or fp32 (Cf)
static __device__ __forceinline__ void gemm_body(
        const u16* __restrict__ A, int lda,
        const u16* __restrict__ Bw,
        u16* Cb, float* Cf, int ldc,
        const float* bias, float scale, int K,
        int m0, int n0)
{
    __shared__ __align__(16) u16 As[128*32];
    __shared__ __align__(16) u16 Bs[128*32];
    int tid = threadIdx.x;
    int srow = tid >> 2, skc = (tid & 3)*8;
    // LDS dest element offset srow*32+skc == tid*8 -> wave-uniform base + lane*16B
    u16* asd = &As[tid*8];
    u16* bsd = &Bs[tid*8];
    const u16* ga0 = &A [(size_t)(m0+srow)*lda + skc];
    const u16* ga1 = &A [(size_t)(m0+srow+64)*lda + skc];
    const u16* gb0 = &Bw[(size_t)(n0+srow)*D_ + skc];
    const u16* gb1 = &Bw[(size_t)(n0+srow+64)*D_ + skc];
    int l = tid & 63, w = tid >> 6;
    int wm = (w & 1)*64, wn = (w >> 1)*64;
    int lr = l & 15, quad = l >> 4;
    f32x4 acc[4][4] = {};
    for (int k0 = 0; k0 < K; k0 += 32){
        __syncthreads();
        GLOAD16(ga0 + k0, asd);
        GLOAD16(ga1 + k0, asd + 2048);
        GLOAD16(gb0 + k0, bsd);
        GLOAD16(gb1 + k0, bsd + 2048);
        __syncthreads();
        bf16x8 af[4], bg[4];
        for (int i = 0; i < 4; ++i) af[i] = *(const bf16x8*)&As[(wm + i*16 + lr)*32 + quad*8];
        for (int j = 0; j < 4; ++j) bg[j] = *(const bf16x8*)&Bs[(wn + j*16 + lr)*32 + quad*8];
        for (int i = 0; i < 4; ++i)
            for (int j = 0; j < 4; ++j)
                acc[i][j] = __builtin_amdgcn_mfma_f32_16x16x32_bf16(af[i], bg[j], acc[i][j], 0, 0, 0);
    }
    for (int j = 0; j < 4; ++j){
        int n = n0 + wn + j*16 + lr;
        float bv = bias ? bias[n] : 0.f;
        for (int i = 0; i < 4; ++i){
            int mrow = m0 + wm + i*16 + quad*4;
            for (int r2 = 0; r2 < 4; ++r2){
                float val = (acc[i][j][r2] + bv) * scale;
                size_t idx = (size_t)(mrow+r2)*ldc + n;
                if (Cf) __builtin_nontemporal_store(val, &Cf[idx]);
                else    Cb[idx] = f2b(val);
            }
        }
    }
}

// fused q/k/v projection: z in [0,12), p=z>>2 (0=q,1=k,2=v), b=z&3
// qkv buffer laid out [p][b][S][D] -> offset z*S*D (since z = p*4+b)
__global__ __launch_bounds__(256) void k_gemm_qkv(
        const u16* x16, const u16* Weff, u16* qkv, const float* qb, const float* vb){
    int z = blockIdx.z, p = z >> 2, b = z & 3;
    const float* bias = (p==0) ? qb : (p==2) ? vb : (const float*)nullptr;
    float scale = (p==2) ? 1.0f : 0.35355339059327373f;   // 64^-0.25
    gemm_body(x16 + (size_t)b*S_*D_, D_,
              Weff + (size_t)z*D_*D_,
              qkv + (size_t)z*S_*D_, (float*)nullptr, D_,
              bias, scale, 1024, blockIdx.x*128, blockIdx.y*128);
}

// output projection: fp32 result
__global__ __launch_bounds__(256) void k_gemm_o(
        const u16* wv, const u16* WeffO, float* out, const float* ob){
    int b = blockIdx.z;
    gemm_body(wv + (size_t)b*S_*D_, D_,
              WeffO + (size_t)b*D_*D_,
              (u16*)nullptr, out + (size_t)b*S_*D_, D_,
              ob, 1.0f, 1024, blockIdx.x*128, blockIdx.y*128);
}

// ---------------- v -> vT[b][h][d][s] ----------------
__global__ void k_vtrans(const u16* v, u16* vT){
    __shared__ __align__(16) u16 Tl[64*72];
    int st = blockIdx.x, bh = blockIdx.y;
    int b = bh >> 4, h = bh & 15;
    int tid = threadIdx.x;
    int row = tid >> 3, c = (tid & 7)*8;
    const u16* vb = v + (size_t)b*S_*D_ + h*64;
    for (int pass = 0; pass < 2; ++pass){
        int r = row + pass*32;
        *(uint4*)&Tl[r*72 + c] = *(const uint4*)&vb[(size_t)(st*64 + r)*D_ + c];
    }
    __syncthreads();
    u16* vTb = vT + (size_t)bh*64*S_;
    for (int pass = 0; pass < 2; ++pass){
        int dr = row + pass*32;
        union { u16 s[8]; uint4 u; } tmp;
        for (int j = 0; j < 8; ++j) tmp.s[j] = Tl[(c+j)*72 + dr];
        *(uint4*)&vTb[(size_t)dr*S_ + st*64 + c] = tmp.u;
    }
}

// ---------------- fused attention: writes qk (fp32, nontemporal) + wv (bf16) ----------------
__global__ __launch_bounds__(256) void k_attn(const u16* q, const u16* k, const u16* vT,
                                              float* qk_out, u16* wv){
    __shared__ __align__(16) u16 Ql[64*72];
    __shared__ __align__(16) u16 Kl[64*72];
    __shared__ __align__(16) u16 Vt[64*72];
    __shared__ __align__(16) u16 Pl[64*72];
    int qt = blockIdx.x, bh = blockIdx.y;
    int b = bh >> 4, h = bh & 15;
    int q0 = qt*64;
    int tid = threadIdx.x;
    int row = tid >> 3, c = (tid & 7)*8;
    int l = tid & 63, w = tid >> 6;
    int lr = l & 15, quad = l >> 4;
    const u16* qp  = q  + (size_t)b*S_*D_ + h*64;
    const u16* kp  = k  + (size_t)b*S_*D_ + h*64;
    const u16* vTp = vT + (size_t)bh*64*S_;
    float* qko = qk_out + (size_t)bh*S_*S_;
    for (int pass = 0; pass < 2; ++pass){
        int r = row + pass*32;
        *(uint4*)&Ql[r*72 + c] = *(const uint4*)&qp[(size_t)(q0 + r)*D_ + c];
    }
    f32x4 oacc[4] = {};
    float m_i[4], l_i[4];
    for (int r2 = 0; r2 < 4; ++r2){ m_i[r2] = -1e30f; l_i[r2] = 0.f; }
    for (int t0 = 0; t0 < S_; t0 += 64){
        __syncthreads();
        for (int pass = 0; pass < 2; ++pass){
            int r = row + pass*32;
            *(uint4*)&Kl[r*72 + c] = *(const uint4*)&kp[(size_t)(t0 + r)*D_ + c];
            *(uint4*)&Vt[r*72 + c] = *(const uint4*)&vTp[(size_t)r*S_ + t0 + c];
        }
        __syncthreads();
        // S = Q K^T  (wave w: q-rows w*16..w*16+15, all 64 t of this tile)
        f32x4 sacc[4] = {};
        for (int kk = 0; kk < 64; kk += 32){
            bf16x8 aq = *(const bf16x8*)&Ql[(w*16 + lr)*72 + kk + quad*8];
            for (int jn = 0; jn < 4; ++jn){
                bf16x8 bk = *(const bf16x8*)&Kl[(jn*16 + lr)*72 + kk + quad*8];
                sacc[jn] = __builtin_amdgcn_mfma_f32_16x16x32_bf16(aq, bk, sacc[jn], 0, 0, 0);
            }
        }
        // write raw scores (pre-softmax) as fp32 — nontemporal, write-only stream
        for (int jn = 0; jn < 4; ++jn)
            for (int r2 = 0; r2 < 4; ++r2){
                int sq = q0 + w*16 + quad*4 + r2;
                __builtin_nontemporal_store(sacc[jn][r2], &qko[(size_t)sq*S_ + t0 + jn*16 + lr]);
            }
        // online softmax (fp32, from fp32 scores); args to exp are all <= 0
        float alpha[4];
        for (int r2 = 0; r2 < 4; ++r2){
            float mx = fmaxf(fmaxf(sacc[0][r2], sacc[1][r2]), fmaxf(sacc[2][r2], sacc[3][r2]));
            for (int off = 1; off < 16; off <<= 1) mx = fmaxf(mx, __shfl_xor(mx, off));
            float mnew = fmaxf(m_i[r2], mx);
            alpha[r2] = __expf(m_i[r2] - mnew);
            m_i[r2] = mnew;
        }
        f32x4 p[4];
        for (int jn = 0; jn < 4; ++jn)
            for (int r2 = 0; r2 < 4; ++r2)
                p[jn][r2] = __expf(sacc[jn][r2] - m_i[r2]);
        for (int r2 = 0; r2 < 4; ++r2){
            float s = p[0][r2] + p[1][r2] + p[2][r2] + p[3][r2];
            for (int off = 1; off < 16; off <<= 1) s += __shfl_xor(s, off);
            l_i[r2] = l_i[r2]*alpha[r2] + s;
        }
        for (int jn = 0; jn < 4; ++jn)
            for (int r2 = 0; r2 < 4; ++r2)
                oacc[jn][r2] *= alpha[r2];
        // P: C/D layout -> LDS -> A layout.
        // Wave w writes rows [w*16, w*16+16) and PV below reads back exactly those
        // rows — intra-wave only, so NO barrier needed (ds-op ordering per wave).
        for (int jn = 0; jn < 4; ++jn)
            for (int r2 = 0; r2 < 4; ++r2)
                Pl[(w*16 + quad*4 + r2)*72 + jn*16 + lr] = f2b(p[jn][r2]);
        // O += P V   (Vt reads are covered by the staging barrier above)
        for (int kk = 0; kk < 64; kk += 32){
            bf16x8 ap = *(const bf16x8*)&Pl[(w*16 + lr)*72 + kk + quad*8];
            for (int jn = 0; jn < 4; ++jn){
                bf16x8 bv = *(const bf16x8*)&Vt[(jn*16 + lr)*72 + kk + quad*8];
                oacc[jn] = __builtin_amdgcn_mfma_f32_16x16x32_bf16(ap, bv, oacc[jn], 0, 0, 0);
            }
        }
    }
    u16* wvp = wv + (size_t)b*S_*D_ + h*64;
    for (int r2 = 0; r2 < 4; ++r2){
        float inv = 1.f / l_i[r2];
        int sq = q0 + w*16 + quad*4 + r2;
        for (int jn = 0; jn < 4; ++jn)
            wvp[(size_t)sq*D_ + jn*16 + lr] = f2b(oacc[jn][r2] * inv);
    }
}

extern "C" void kernel_launch(void* const* d_in, const int* in_sizes, int n_in,
                              void* d_out, int out_size, void* d_ws, size_t ws_size,
                              hipStream_t stream){
    const float* x      = (const float*)d_in[0];
    const float* conv_w = (const float*)d_in[1];
    const float* conv_b = (const float*)d_in[2];
    const float* pool_w = (const float*)d_in[3];
    const float* pool_b = (const float*)d_in[4];
    const float* rlin_w = (const float*)d_in[5];
    const float* rlin_b = (const float*)d_in[6];
    const float* qW = (const float*)d_in[7];
    const float* qb = (const float*)d_in[8];
    const float* qA = (const float*)d_in[9];
    const float* qB = (const float*)d_in[10];
    const float* kW = (const float*)d_in[11];
    const float* kA = (const float*)d_in[12];
    const float* kB = (const float*)d_in[13];
    const float* vW = (const float*)d_in[14];
    const float* vb = (const float*)d_in[15];
    const float* vA = (const float*)d_in[16];
    const float* vB = (const float*)d_in[17];
    const float* oW = (const float*)d_in[18];
    const float* ob = (const float*)d_in[19];
    const float* oA = (const float*)d_in[20];
    const float* oB = (const float*)d_in[21];

    char* ws = (char*)d_ws;
    float* route  = (float*)(ws + 0);        // 128 B
    float* constk = (float*)(ws + 512);      // 4 B
    float* cwp    = (float*)(ws + 1024);     // 12 KB   (ends 13,312)
    float* h      = (float*)(ws + 16384);    // 48 KB   (ends 65,536)
    float* wsm    = (float*)(ws + 65536);    // 16 KB   (ends 81,920)
    float* xwl    = (float*)(ws + 81920);    // 48 KB   (ends 131,072)
    float* pooled = (float*)(ws + 131072);   // 16 KB   (ends 147,456)
    u16* AeffT = (u16*)(ws + (1ull  << 20));                 // 2 MB
    u16* B16   = (u16*)(ws + (3ull  << 20));                 // 512 KB (q,k,v,o B)
    u16* Weff  = (u16*)(ws + (4ull  << 20));                 // 32 MB
    u16* x16   = (u16*)(ws + (36ull << 20));                 // 8 MB
    u16* qkv   = (u16*)(ws + (44ull << 20));                 // 24 MB: [p][b][S][D], p=0:q 1:k 2:v
    u16* qbuf  = qkv + 0*(size_t)B_*S_*D_;
    u16* kbuf  = qkv + 1*(size_t)B_*S_*D_;
    u16* vbuf  = qkv + 2*(size_t)B_*S_*D_;
    u16* vTbuf = (u16*)(ws + (68ull << 20));                 // 8 MB  -> total 76 MB
    u16* wvbuf = vbuf;                                       // v dead after k_vtrans

    float* out    = (float*)d_out;
    float* qk_out = out + (size_t)B_*S_*D_;

    const long long sDD = (long long)D_*D_;

    // fp32 -> bf16 copies (k_cvtB also zeroes cwp for the atomic accumulate)
    k_cvt4<<<2048, 256, 0, stream>>>((const float4*)x, (ushort4*)x16, B_*S_*D_/4);
    k_cvtB<<<dim3(16, 4), 256, 0, stream>>>(qB, kB, vB, oB, B16, cwp);

    k_cwp   <<<dim3(13, 8), 256, 0, stream>>>(conv_w, conv_b, pool_w, pool_b, cwp, constk);
    k_h     <<<dim3(S_/4, B_), 256, 0, stream>>>(x, cwp, h);
    k_softw <<<B_, 256, 0, stream>>>(h, constk, wsm);
    k_xw    <<<dim3(16, B_), 256, 0, stream>>>(x, wsm, xwl);
    k_pooled<<<256, 256, 0, stream>>>(conv_w, conv_b, xwl, pooled);
    k_route <<<1, 256, 0, stream>>>(pooled, rlin_w, rlin_b, route);
    k_aeff  <<<dim3(16, B_, 4), 256, 0, stream>>>(qA, kA, vA, oA, route, AeffT);
    k_weff  <<<dim3(8, 8, 16), 256, 0, stream>>>(B16, qW, kW, vW, oW, AeffT, Weff);

    // fused q/k/v projections: 768 blocks = 3 blocks/CU
    k_gemm_qkv<<<dim3(8,8,12), 256, 0, stream>>>(x16, Weff, qkv, qb, vb);

    k_vtrans<<<dim3(16, B_*H_), 256, 0, stream>>>(vbuf, vTbuf);
    k_attn  <<<dim3(16, B_*H_), 256, 0, stream>>>(qbuf, kbuf, vTbuf, qk_out, wvbuf);
    k_gemm_o<<<dim3(8,8,B_), 256, 0, stream>>>(wvbuf, Weff + 12*sDD, out, ob);
}

// Round 5
// 615.119 us; speedup vs baseline: 1.2333x; 1.1131x over previous
//
#include <hip/hip_runtime.h>
#include <cstdint>

typedef unsigned short u16;
typedef __bf16 bf16_t;
typedef bf16_t bf16x8 __attribute__((ext_vector_type(8)));
typedef float f32x4 __attribute__((ext_vector_type(4)));

#define B_ 4
#define S_ 1024
#define D_ 1024
#define E_ 8
#define R_ 8
#define H_ 16
#define DH_ 64

// direct global -> LDS, 16B per lane (dest must be wave-uniform base + lane*16)
#define GLOAD16(gp, lp) __builtin_amdgcn_global_load_lds( \
        (const __attribute__((address_space(1))) void*)(gp), \
        (__attribute__((address_space(3))) void*)(lp), 16, 0, 0)

static __device__ __forceinline__ u16 f2b(float f){
    union { float f; uint32_t i; } v; v.f = f;
    uint32_t i = v.i;
    uint32_t r = i + 0x7FFFu + ((i >> 16) & 1u);   // RNE
    return (u16)(r >> 16);
}

// ---------------- fused fp32->bf16 converts (x + 4 LoRA B) + cwp zero ----------------
__global__ void k_cvtall(const float4* x, const float* qB, const float* kB,
                         const float* vB, const float* oB,
                         ushort4* x16, ushort4* B16v, float4* cwp4){
    const int NX = B_*S_*D_/4;          // 1,048,576 float4
    const int NB = E_*D_*R_/4;          // 16,384 float4 per B matrix
    const int NC = 3*D_/4;              // 768 float4 (cwp zero)
    const int NTOT = NX + 4*NB + NC;
    for (int i = blockIdx.x*blockDim.x + threadIdx.x; i < NTOT; i += gridDim.x*blockDim.x){
        if (i < NX){
            float4 v = x[i];
            ushort4 o; o.x=f2b(v.x); o.y=f2b(v.y); o.z=f2b(v.z); o.w=f2b(v.w);
            x16[i] = o;
        } else if (i < NX + 4*NB){
            int j = i - NX;
            int p = j >> 14, e = j & (NB-1);
            const float4* src = (p==0)?(const float4*)qB:(p==1)?(const float4*)kB
                              :(p==2)?(const float4*)vB:(const float4*)oB;
            float4 v = src[e];
            ushort4 o; o.x=f2b(v.x); o.y=f2b(v.y); o.z=f2b(v.z); o.w=f2b(v.w);
            B16v[p*NB + e] = o;
        } else {
            cwp4[i - NX - 4*NB] = make_float4(0.f,0.f,0.f,0.f);
        }
    }
}

// ---------------- router: cw_pool (atomic partials over o-chunks) + const term ----------------
__global__ void k_cwp(const float* conv_w, const float* conv_b, const float* pool_w,
                      const float* pool_b, float* cwp, float* constk){
    __shared__ float red[256];
    int bid = blockIdx.x, ob = blockIdx.y;
    if (bid < 12){
        int j = bid*256 + threadIdx.x;       // j = t*1024 + i
        int t = j >> 10, i = j & 1023;
        float acc = 0.f;
        for (int o = ob*128; o < (ob+1)*128; ++o)
            acc += pool_w[o] * conv_w[(size_t)o*3072 + i*3 + t];
        atomicAdd(&cwp[j], acc);
    } else if (ob == 0){
        float acc = 0.f;
        for (int o = threadIdx.x; o < D_; o += 256) acc += pool_w[o] * conv_b[o];
        red[threadIdx.x] = acc; __syncthreads();
        for (int s = 128; s > 0; s >>= 1){
            if (threadIdx.x < s) red[threadIdx.x] += red[threadIdx.x+s];
            __syncthreads();
        }
        if (threadIdx.x == 0) *constk = red[0] + pool_b[0];
    }
}

// ---------------- router: h_t[b,s] = cwp_t . x[b,s]  (x read once, coalesced) ----------------
__global__ void k_h(const float* x, const float* cwp, float* h){
    int b = blockIdx.y;
    int w = threadIdx.x >> 6, lane = threadIdx.x & 63;
    int s = blockIdx.x*4 + w;
    const float4* xr = (const float4*)(x + ((size_t)b*S_ + s)*D_);
    const float4* c0 = (const float4*)(cwp);
    const float4* c1 = (const float4*)(cwp + D_);
    const float4* c2 = (const float4*)(cwp + 2*D_);
    float a0 = 0.f, a1 = 0.f, a2 = 0.f;
    #pragma unroll
    for (int it = 0; it < 4; ++it){
        float4 v  = xr[it*64 + lane];
        float4 w0 = c0[it*64 + lane];
        float4 w1 = c1[it*64 + lane];
        float4 w2 = c2[it*64 + lane];
        a0 += v.x*w0.x + v.y*w0.y + v.z*w0.z + v.w*w0.w;
        a1 += v.x*w1.x + v.y*w1.y + v.z*w1.z + v.w*w1.w;
        a2 += v.x*w2.x + v.y*w2.y + v.z*w2.z + v.w*w2.w;
    }
    for (int off = 32; off; off >>= 1){
        a0 += __shfl_down(a0, off);
        a1 += __shfl_down(a1, off);
        a2 += __shfl_down(a2, off);
    }
    if (lane == 0){
        h[(0*B_ + b)*S_ + s] = a0;
        h[(1*B_ + b)*S_ + s] = a1;
        h[(2*B_ + b)*S_ + s] = a2;
    }
}

// ---------------- router: xw (softmax over seq computed in-block from h) ----------------
__global__ void k_xw(const float* x, const float* h, const float* constk, float* xwl){
    int b = blockIdx.y;
    int lane = threadIdx.x & 63;
    int w = threadIdx.x >> 6;
    int i = blockIdx.x*64 + lane;
    __shared__ float red[256];
    __shared__ float wsm_l[S_];
    __shared__ float red3[3][4][64];
    const float* h0 = h + (0*B_ + b)*S_;
    const float* h1 = h + (1*B_ + b)*S_;
    const float* h2 = h + (2*B_ + b)*S_;
    float ck = *constk;
    // scores -> wsm_l (raw), block max
    float mx = -1e30f;
    for (int s = threadIdx.x; s < S_; s += 256){
        float v = h1[s] + ck;
        if (s >= 1)   v += h0[s-1];
        if (s+1 < S_) v += h2[s+1];
        wsm_l[s] = v;
        mx = fmaxf(mx, v);
    }
    red[threadIdx.x] = mx; __syncthreads();
    for (int st = 128; st > 0; st >>= 1){
        if (threadIdx.x < st) red[threadIdx.x] = fmaxf(red[threadIdx.x], red[threadIdx.x+st]);
        __syncthreads();
    }
    mx = red[0]; __syncthreads();
    float sum = 0.f;
    for (int s = threadIdx.x; s < S_; s += 256) sum += __expf(wsm_l[s] - mx);
    red[threadIdx.x] = sum; __syncthreads();
    for (int st = 128; st > 0; st >>= 1){
        if (threadIdx.x < st) red[threadIdx.x] += red[threadIdx.x+st];
        __syncthreads();
    }
    float inv = 1.f / red[0];
    __syncthreads();
    for (int s = threadIdx.x; s < S_; s += 256)
        wsm_l[s] = __expf(wsm_l[s] - mx) * inv;
    __syncthreads();
    // weighted sums: wave w owns sequence quarter
    const float* xb = x + (size_t)b*S_*D_;
    float a0 = 0.f, a1 = 0.f, a2 = 0.f;
    #pragma unroll 4
    for (int r = w*256; r < (w+1)*256; ++r){
        float xv = xb[(size_t)r*D_ + i];
        float w1 = wsm_l[r];
        float w0 = (r+1 < S_) ? wsm_l[r+1] : 0.f;
        float w2 = (r >= 1)   ? wsm_l[r-1] : 0.f;
        a0 += w0*xv; a1 += w1*xv; a2 += w2*xv;
    }
    red3[0][w][lane] = a0; red3[1][w][lane] = a1; red3[2][w][lane] = a2;
    __syncthreads();
    if (w == 0){
        a0 = red3[0][0][lane] + red3[0][1][lane] + red3[0][2][lane] + red3[0][3][lane];
        a1 = red3[1][0][lane] + red3[1][1][lane] + red3[1][2][lane] + red3[1][3][lane];
        a2 = red3[2][0][lane] + red3[2][1][lane] + red3[2][2][lane] + red3[2][3][lane];
        xwl[b*3072 + i*3 + 0] = a0;
        xwl[b*3072 + i*3 + 1] = a1;
        xwl[b*3072 + i*3 + 2] = a2;
    }
}

// ---------------- router: pooled[b,o] ----------------
__global__ void k_pooled(const float* conv_w, const float* conv_b, const float* xwl, float* pooled){
    int o = blockIdx.x*4 + (threadIdx.x >> 6);
    int lane = threadIdx.x & 63;
    const float* cw = conv_w + (size_t)o*3072;
    float a0=0.f, a1=0.f, a2=0.f, a3=0.f;
    for (int j = lane; j < 3072; j += 64){
        float c = cw[j];
        a0 += c*xwl[j]; a1 += c*xwl[3072+j]; a2 += c*xwl[2*3072+j]; a3 += c*xwl[3*3072+j];
    }
    for (int off = 32; off; off >>= 1){
        a0 += __shfl_down(a0, off); a1 += __shfl_down(a1, off);
        a2 += __shfl_down(a2, off); a3 += __shfl_down(a3, off);
    }
    if (lane == 0){
        float cb = conv_b[o];
        pooled[0*D_+o] = a0+cb; pooled[1*D_+o] = a1+cb;
        pooled[2*D_+o] = a2+cb; pooled[3*D_+o] = a3+cb;
    }
}

// ---------------- router: logits + softmax -> route[b,e] ----------------
__global__ void k_route(const float* pooled, const float* rlin_w, const float* rlin_b, float* route){
    __shared__ float lg[B_][E_];
    int t = threadIdx.x;
    int b = t >> 6, e = (t >> 3) & 7, part = t & 7;
    float acc = 0.f;
    for (int o = part; o < D_; o += 8) acc += pooled[b*D_+o] * rlin_w[e*D_+o];
    acc += __shfl_down(acc, 4); acc += __shfl_down(acc, 2); acc += __shfl_down(acc, 1);
    if (part == 0) lg[b][e] = acc + rlin_b[e];
    __syncthreads();
    if (t < B_){
        float mx = -1e30f;
        for (int e2 = 0; e2 < E_; ++e2) mx = fmaxf(mx, lg[t][e2]);
        float ex[E_], sum = 0.f;
        for (int e2 = 0; e2 < E_; ++e2){ ex[e2] = expf(lg[t][e2]-mx); sum += ex[e2]; }
        for (int e2 = 0; e2 < E_; ++e2) route[t*E_+e2] = ex[e2]/sum;
    }
}

// ---------------- AeffT[z][d][k] = 2*route[b,e]*A_p[e,r,d], k=e*8+r ----------------
__global__ void k_aeff(const float* qA, const float* kA, const float* vA, const float* oA,
                       const float* route, u16* AeffT){
    int dc = blockIdx.x, b = blockIdx.y, p = blockIdx.z;
    const float* Ap = (p==0)?qA:(p==1)?kA:(p==2)?vA:oA;
    int z = p*4 + b;
    for (int idx = threadIdx.x; idx < 64*64; idx += 256){
        int dl = idx >> 6, kk = idx & 63;
        int d = dc*64 + dl;
        int e = kk >> 3, r = kk & 7;
        float v = 2.0f * route[b*E_+e] * Ap[(size_t)(e*R_+r)*D_ + d];
        AeffT[((size_t)z*D_ + d)*64 + kk] = f2b(v);
    }
}

// ---------------- Weff[z][n][d] = W_p[n,d] + Bfold[n,:] @ AeffT[:,d]  (K=64 MFMA) ----------------
__global__ __launch_bounds__(256) void k_weff(
        const u16* B16,
        const float* qW, const float* kW, const float* vW, const float* oW,
        const u16* AeffT, u16* Weff){
    __shared__ __align__(16) u16 As[128*64];
    __shared__ __align__(16) u16 Bs[128*64];
    int z = blockIdx.z, p = z >> 2;
    const u16* Bp = B16 + (size_t)p*E_*D_*R_;
    const float* Wp = (p==0)?qW:(p==1)?kW:(p==2)?vW:oW;
    int n0 = blockIdx.x*128, d0 = blockIdx.y*128;
    int tid = threadIdx.x;
    int e = tid & 7, row = tid >> 3;
    for (int pass = 0; pass < 4; ++pass){
        int rr = row + pass*32;
        GLOAD16(&Bp[((size_t)e*D_ + (n0+rr))*R_],           &As[pass*2048 + tid*8]);
        GLOAD16(&AeffT[((size_t)z*D_ + (d0+rr))*64 + e*8],  &Bs[pass*2048 + tid*8]);
    }
    __syncthreads();
    int l = tid & 63, w = tid >> 6;
    int wm = (w & 1)*64, wn = (w >> 1)*64;
    int lr = l & 15, quad = l >> 4;
    f32x4 acc[4][4] = {};
    for (int kk = 0; kk < 64; kk += 32){
        bf16x8 af[4], bg[4];
        for (int i = 0; i < 4; ++i) af[i] = *(const bf16x8*)&As[(wm + i*16 + lr)*64 + kk + quad*8];
        for (int j = 0; j < 4; ++j) bg[j] = *(const bf16x8*)&Bs[(wn + j*16 + lr)*64 + kk + quad*8];
        for (int i = 0; i < 4; ++i)
            for (int j = 0; j < 4; ++j)
                acc[i][j] = __builtin_amdgcn_mfma_f32_16x16x32_bf16(af[i], bg[j], acc[i][j], 0, 0, 0);
    }
    u16* Wz = Weff + (size_t)z*D_*D_;
    for (int i = 0; i < 4; ++i)
        for (int j = 0; j < 4; ++j)
            for (int r2 = 0; r2 < 4; ++r2){
                int n = n0 + wm + i*16 + quad*4 + r2;
                int d = d0 + wn + j*16 + lr;
                Wz[(size_t)n*D_ + d] = f2b(acc[i][j][r2] + Wp[(size_t)n*D_ + d]);
            }
}

// ---------------- shared 128x128 MFMA GEMM body (direct-to-LDS staging) ----------------
static __device__ __forceinline__ void gemm_body(
        const u16* __restrict__ A, int lda,
        const u16* __restrict__ Bw,
        u16* Cb, float* Cf, int ldc,
        const float* bias, float scale, int K,
        int m0, int n0)
{
    __shared__ __align__(16) u16 As[128*32];
    __shared__ __align__(16) u16 Bs[128*32];
    int tid = threadIdx.x;
    int srow = tid >> 2, skc = (tid & 3)*8;
    u16* asd = &As[tid*8];
    u16* bsd = &Bs[tid*8];
    const u16* ga0 = &A [(size_t)(m0+srow)*lda + skc];
    const u16* ga1 = &A [(size_t)(m0+srow+64)*lda + skc];
    const u16* gb0 = &Bw[(size_t)(n0+srow)*D_ + skc];
    const u16* gb1 = &Bw[(size_t)(n0+srow+64)*D_ + skc];
    int l = tid & 63, w = tid >> 6;
    int wm = (w & 1)*64, wn = (w >> 1)*64;
    int lr = l & 15, quad = l >> 4;
    f32x4 acc[4][4] = {};
    for (int k0 = 0; k0 < K; k0 += 32){
        __syncthreads();
        GLOAD16(ga0 + k0, asd);
        GLOAD16(ga1 + k0, asd + 2048);
        GLOAD16(gb0 + k0, bsd);
        GLOAD16(gb1 + k0, bsd + 2048);
        __syncthreads();
        bf16x8 af[4], bg[4];
        for (int i = 0; i < 4; ++i) af[i] = *(const bf16x8*)&As[(wm + i*16 + lr)*32 + quad*8];
        for (int j = 0; j < 4; ++j) bg[j] = *(const bf16x8*)&Bs[(wn + j*16 + lr)*32 + quad*8];
        for (int i = 0; i < 4; ++i)
            for (int j = 0; j < 4; ++j)
                acc[i][j] = __builtin_amdgcn_mfma_f32_16x16x32_bf16(af[i], bg[j], acc[i][j], 0, 0, 0);
    }
    for (int j = 0; j < 4; ++j){
        int n = n0 + wn + j*16 + lr;
        float bv = bias ? bias[n] : 0.f;
        for (int i = 0; i < 4; ++i){
            int mrow = m0 + wm + i*16 + quad*4;
            for (int r2 = 0; r2 < 4; ++r2){
                float val = (acc[i][j][r2] + bv) * scale;
                size_t idx = (size_t)(mrow+r2)*ldc + n;
                if (Cf) __builtin_nontemporal_store(val, &Cf[idx]);
                else    Cb[idx] = f2b(val);
            }
        }
    }
}

// fused q/k/v projection
__global__ __launch_bounds__(256) void k_gemm_qkv(
        const u16* x16, const u16* Weff, u16* qkv, const float* qb, const float* vb){
    int z = blockIdx.z, p = z >> 2, b = z & 3;
    const float* bias = (p==0) ? qb : (p==2) ? vb : (const float*)nullptr;
    float scale = (p==2) ? 1.0f : 0.35355339059327373f;   // 64^-0.25
    gemm_body(x16 + (size_t)b*S_*D_, D_,
              Weff + (size_t)z*D_*D_,
              qkv + (size_t)z*S_*D_, (float*)nullptr, D_,
              bias, scale, 1024, blockIdx.x*128, blockIdx.y*128);
}

// output projection: fp32 result
__global__ __launch_bounds__(256) void k_gemm_o(
        const u16* wv, const u16* WeffO, float* out, const float* ob){
    int b = blockIdx.z;
    gemm_body(wv + (size_t)b*S_*D_, D_,
              WeffO + (size_t)b*D_*D_,
              (u16*)nullptr, out + (size_t)b*S_*D_, D_,
              ob, 1.0f, 1024, blockIdx.x*128, blockIdx.y*128);
}

// ---------------- v -> vT[b][h][d][s] ----------------
__global__ void k_vtrans(const u16* v, u16* vT){
    __shared__ __align__(16) u16 Tl[64*72];
    int st = blockIdx.x, bh = blockIdx.y;
    int b = bh >> 4, h = bh & 15;
    int tid = threadIdx.x;
    int row = tid >> 3, c = (tid & 7)*8;
    const u16* vb = v + (size_t)b*S_*D_ + h*64;
    for (int pass = 0; pass < 2; ++pass){
        int r = row + pass*32;
        *(uint4*)&Tl[r*72 + c] = *(const uint4*)&vb[(size_t)(st*64 + r)*D_ + c];
    }
    __syncthreads();
    u16* vTb = vT + (size_t)bh*64*S_;
    for (int pass = 0; pass < 2; ++pass){
        int dr = row + pass*32;
        union { u16 s[8]; uint4 u; } tmp;
        for (int j = 0; j < 8; ++j) tmp.s[j] = Tl[(c+j)*72 + dr];
        *(uint4*)&vTb[(size_t)dr*S_ + st*64 + c] = tmp.u;
    }
}

// ---------------- fused attention: gload_lds + XOR-swizzled LDS (64-stride) ----------------
// swizzle: 16B unit index ^= (row & 7); source pre-swizzled, reads swizzled, dest linear
__global__ __launch_bounds__(256) void k_attn(const u16* q, const u16* k, const u16* vT,
                                              float* qk_out, u16* wv){
    __shared__ __align__(16) u16 Ql[64*64];
    __shared__ __align__(16) u16 Kl[64*64];
    __shared__ __align__(16) u16 Vt[64*64];
    __shared__ __align__(16) u16 Pl[64*64];
    int qt = blockIdx.x, bh = blockIdx.y;
    int b = bh >> 4, h = bh & 15;
    int q0 = qt*64;
    int tid = threadIdx.x;
    int l = tid & 63, w = tid >> 6;
    int lr = l & 15, quad = l >> 4;
    int srow = tid >> 3;                                  // w*8 + (l>>3) : 0..31
    int scol = (((tid & 7) ^ ((tid >> 3) & 7))) * 8;      // inverse-swizzled source elems
    int sdst = tid * 8;                                   // linear dest (lane*16B)
    const u16* qp  = q  + (size_t)b*S_*D_ + h*64;
    const u16* kp  = k  + (size_t)b*S_*D_ + h*64;
    const u16* vTp = vT + (size_t)bh*64*S_;
    float* qko = qk_out + (size_t)bh*S_*S_;
    // stage Q once (swizzled)
    GLOAD16(&qp[(size_t)(q0 + srow)*D_ + scol],      &Ql[sdst]);
    GLOAD16(&qp[(size_t)(q0 + srow + 32)*D_ + scol], &Ql[sdst + 2048]);
    int rsw = lr & 7;                                     // row&7 for all MFMA-read rows
    f32x4 oacc[4] = {};
    float m_i[4], l_i[4];
    for (int r2 = 0; r2 < 4; ++r2){ m_i[r2] = -1e30f; l_i[r2] = 0.f; }
    for (int t0 = 0; t0 < S_; t0 += 64){
        __syncthreads();
        GLOAD16(&kp[(size_t)(t0 + srow)*D_ + scol],        &Kl[sdst]);
        GLOAD16(&kp[(size_t)(t0 + srow + 32)*D_ + scol],   &Kl[sdst + 2048]);
        GLOAD16(&vTp[(size_t)srow*S_ + t0 + scol],         &Vt[sdst]);
        GLOAD16(&vTp[(size_t)(srow + 32)*S_ + t0 + scol],  &Vt[sdst + 2048]);
        __syncthreads();
        // S = Q K^T
        f32x4 sacc[4] = {};
        for (int kk = 0; kk < 64; kk += 32){
            int un = ((quad + (kk >> 3)) ^ rsw) * 8;
            bf16x8 aq = *(const bf16x8*)&Ql[(w*16 + lr)*64 + un];
            for (int jn = 0; jn < 4; ++jn){
                bf16x8 bk = *(const bf16x8*)&Kl[(jn*16 + lr)*64 + un];
                sacc[jn] = __builtin_amdgcn_mfma_f32_16x16x32_bf16(aq, bk, sacc[jn], 0, 0, 0);
            }
        }
        // raw scores -> fp32 nontemporal stream
        for (int jn = 0; jn < 4; ++jn)
            for (int r2 = 0; r2 < 4; ++r2){
                int sq = q0 + w*16 + quad*4 + r2;
                __builtin_nontemporal_store(sacc[jn][r2], &qko[(size_t)sq*S_ + t0 + jn*16 + lr]);
            }
        // online softmax
        float alpha[4];
        for (int r2 = 0; r2 < 4; ++r2){
            float mx = fmaxf(fmaxf(sacc[0][r2], sacc[1][r2]), fmaxf(sacc[2][r2], sacc[3][r2]));
            for (int off = 1; off < 16; off <<= 1) mx = fmaxf(mx, __shfl_xor(mx, off));
            float mnew = fmaxf(m_i[r2], mx);
            alpha[r2] = __expf(m_i[r2] - mnew);
            m_i[r2] = mnew;
        }
        f32x4 p[4];
        for (int jn = 0; jn < 4; ++jn)
            for (int r2 = 0; r2 < 4; ++r2)
                p[jn][r2] = __expf(sacc[jn][r2] - m_i[r2]);
        for (int r2 = 0; r2 < 4; ++r2){
            float s = p[0][r2] + p[1][r2] + p[2][r2] + p[3][r2];
            for (int off = 1; off < 16; off <<= 1) s += __shfl_xor(s, off);
            l_i[r2] = l_i[r2]*alpha[r2] + s;
        }
        for (int jn = 0; jn < 4; ++jn)
            for (int r2 = 0; r2 < 4; ++r2)
                oacc[jn][r2] *= alpha[r2];
        // P -> LDS (swizzled); intra-wave rows only, no barrier needed
        for (int jn = 0; jn < 4; ++jn)
            for (int r2 = 0; r2 < 4; ++r2){
                int pr = w*16 + quad*4 + r2;
                int tu = (jn*2 + (lr >> 3)) ^ (pr & 7);
                Pl[pr*64 + tu*8 + (lr & 7)] = f2b(p[jn][r2]);
            }
        // O += P V
        for (int kk = 0; kk < 64; kk += 32){
            int un = ((quad + (kk >> 3)) ^ rsw) * 8;
            bf16x8 ap = *(const bf16x8*)&Pl[(w*16 + lr)*64 + un];
            for (int jn = 0; jn < 4; ++jn){
                bf16x8 bv = *(const bf16x8*)&Vt[(jn*16 + lr)*64 + un];
                oacc[jn] = __builtin_amdgcn_mfma_f32_16x16x32_bf16(ap, bv, oacc[jn], 0, 0, 0);
            }
        }
    }
    u16* wvp = wv + (size_t)b*S_*D_ + h*64;
    for (int r2 = 0; r2 < 4; ++r2){
        float inv = 1.f / l_i[r2];
        int sq = q0 + w*16 + quad*4 + r2;
        for (int jn = 0; jn < 4; ++jn)
            wvp[(size_t)sq*D_ + jn*16 + lr] = f2b(oacc[jn][r2] * inv);
    }
}

extern "C" void kernel_launch(void* const* d_in, const int* in_sizes, int n_in,
                              void* d_out, int out_size, void* d_ws, size_t ws_size,
                              hipStream_t stream){
    const float* x      = (const float*)d_in[0];
    const float* conv_w = (const float*)d_in[1];
    const float* conv_b = (const float*)d_in[2];
    const float* pool_w = (const float*)d_in[3];
    const float* pool_b = (const float*)d_in[4];
    const float* rlin_w = (const float*)d_in[5];
    const float* rlin_b = (const float*)d_in[6];
    const float* qW = (const float*)d_in[7];
    const float* qb = (const float*)d_in[8];
    const float* qA = (const float*)d_in[9];
    const float* qB = (const float*)d_in[10];
    const float* kW = (const float*)d_in[11];
    const float* kA = (const float*)d_in[12];
    const float* kB = (const float*)d_in[13];
    const float* vW = (const float*)d_in[14];
    const float* vb = (const float*)d_in[15];
    const float* vA = (const float*)d_in[16];
    const float* vB = (const float*)d_in[17];
    const float* oW = (const float*)d_in[18];
    const float* ob = (const float*)d_in[19];
    const float* oA = (const float*)d_in[20];
    const float* oB = (const float*)d_in[21];

    char* ws = (char*)d_ws;
    float* route  = (float*)(ws + 0);        // 128 B
    float* constk = (float*)(ws + 512);      // 4 B
    float* cwp    = (float*)(ws + 1024);     // 12 KB
    float* h      = (float*)(ws + 16384);    // 48 KB
    float* xwl    = (float*)(ws + 81920);    // 48 KB
    float* pooled = (float*)(ws + 131072);   // 16 KB
    u16* AeffT = (u16*)(ws + (1ull  << 20));                 // 2 MB
    u16* B16   = (u16*)(ws + (3ull  << 20));                 // 512 KB
    u16* Weff  = (u16*)(ws + (4ull  << 20));                 // 32 MB
    u16* x16   = (u16*)(ws + (36ull << 20));                 // 8 MB
    u16* qkv   = (u16*)(ws + (44ull << 20));                 // 24 MB: [p][b][S][D]
    u16* qbuf  = qkv + 0*(size_t)B_*S_*D_;
    u16* kbuf  = qkv + 1*(size_t)B_*S_*D_;
    u16* vbuf  = qkv + 2*(size_t)B_*S_*D_;
    u16* vTbuf = (u16*)(ws + (68ull << 20));                 // 8 MB
    u16* wvbuf = vbuf;                                       // v dead after k_vtrans

    float* out    = (float*)d_out;
    float* qk_out = out + (size_t)B_*S_*D_;

    const long long sDD = (long long)D_*D_;

    // fused converts + cwp zero
    k_cvtall<<<2048, 256, 0, stream>>>((const float4*)x, qB, kB, vB, oB,
                                       (ushort4*)x16, (ushort4*)B16, (float4*)cwp);

    k_cwp   <<<dim3(13, 8), 256, 0, stream>>>(conv_w, conv_b, pool_w, pool_b, cwp, constk);
    k_h     <<<dim3(S_/4, B_), 256, 0, stream>>>(x, cwp, h);
    k_xw    <<<dim3(16, B_), 256, 0, stream>>>(x, h, constk, xwl);
    k_pooled<<<256, 256, 0, stream>>>(conv_w, conv_b, xwl, pooled);
    k_route <<<1, 256, 0, stream>>>(pooled, rlin_w, rlin_b, route);
    k_aeff  <<<dim3(16, B_, 4), 256, 0, stream>>>(qA, kA, vA, oA, route, AeffT);
    k_weff  <<<dim3(8, 8, 16), 256, 0, stream>>>(B16, qW, kW, vW, oW, AeffT, Weff);

    // fused q/k/v projections: 768 blocks = 3 blocks/CU
    k_gemm_qkv<<<dim3(8,8,12), 256, 0, stream>>>(x16, Weff, qkv, qb, vb);

    k_vtrans<<<dim3(16, B_*H_), 256, 0, stream>>>(vbuf, vTbuf);
    k_attn  <<<dim3(16, B_*H_), 256, 0, stream>>>(qbuf, kbuf, vTbuf, qk_out, wvbuf);
    k_gemm_o<<<dim3(8,8,B_), 256, 0, stream>>>(wvbuf, Weff + 12*sDD, out, ob);
}

// Round 6
// 577.376 us; speedup vs baseline: 1.3139x; 1.0654x over previous
//
#include <hip/hip_runtime.h>
#include <cstdint>

typedef unsigned short u16;
typedef __bf16 bf16_t;
typedef bf16_t bf16x8 __attribute__((ext_vector_type(8)));
typedef float f32x4 __attribute__((ext_vector_type(4)));

#define B_ 4
#define S_ 1024
#define D_ 1024
#define E_ 8
#define R_ 8
#define H_ 16
#define DH_ 64

// direct global -> LDS, 16B per lane (dest must be wave-uniform base + lane*16)
#define GLOAD16(gp, lp) __builtin_amdgcn_global_load_lds( \
        (const __attribute__((address_space(1))) void*)(gp), \
        (__attribute__((address_space(3))) void*)(lp), 16, 0, 0)

static __device__ __forceinline__ u16 f2b(float f){
    union { float f; uint32_t i; } v; v.f = f;
    uint32_t i = v.i;
    uint32_t r = i + 0x7FFFu + ((i >> 16) & 1u);   // RNE
    return (u16)(r >> 16);
}

// ---------------- k_pre: fp32->bf16 converts (x + 4 LoRA B) + cwp partials + constk ----------------
// blocks [0,2048): converts; [2048,2144): cwp partial (no atomics — disjoint ob slices);
// block 2144: constk.
__global__ void k_pre(const float4* x, const float* qB, const float* kB,
                      const float* vB, const float* oB,
                      const float* conv_w, const float* conv_b,
                      const float* pool_w, const float* pool_b,
                      ushort4* x16, ushort4* B16v, float* cwp_part, float* constk){
    const int NCVT = 2048;
    const int NX = B_*S_*D_/4;          // 1,048,576 float4
    const int NB = E_*D_*R_/4;          // 16,384 float4 per B matrix
    if (blockIdx.x < NCVT){
        const int NTOT = NX + 4*NB;
        for (int i = blockIdx.x*blockDim.x + threadIdx.x; i < NTOT; i += NCVT*blockDim.x){
            if (i < NX){
                float4 v = x[i];
                ushort4 o; o.x=f2b(v.x); o.y=f2b(v.y); o.z=f2b(v.z); o.w=f2b(v.w);
                x16[i] = o;
            } else {
                int j = i - NX;
                int p = j >> 14, e = j & (NB-1);
                const float4* src = (p==0)?(const float4*)qB:(p==1)?(const float4*)kB
                                  :(p==2)?(const float4*)vB:(const float4*)oB;
                float4 v = src[e];
                ushort4 o; o.x=f2b(v.x); o.y=f2b(v.y); o.z=f2b(v.z); o.w=f2b(v.w);
                B16v[p*NB + e] = o;
            }
        }
    } else {
        int idx = blockIdx.x - NCVT;
        if (idx < 96){
            int bid = idx % 12, ob = idx / 12;
            int j = bid*256 + threadIdx.x;       // j = t*1024 + i
            int t = j >> 10, i = j & 1023;
            float acc = 0.f;
            for (int o = ob*128; o < ob*128 + 128; ++o)
                acc += pool_w[o] * conv_w[(size_t)o*3072 + i*3 + t];
            cwp_part[ob*3072 + j] = acc;
        } else {
            __shared__ float red[256];
            float acc = 0.f;
            for (int o = threadIdx.x; o < D_; o += 256) acc += pool_w[o] * conv_b[o];
            red[threadIdx.x] = acc; __syncthreads();
            for (int s = 128; s > 0; s >>= 1){
                if (threadIdx.x < s) red[threadIdx.x] += red[threadIdx.x+s];
                __syncthreads();
            }
            if (threadIdx.x == 0) *constk = red[0] + pool_b[0];
        }
    }
}

// ---------------- router: h_t[b,s] = cwp_t . x[b,s]  (sums the 8 cwp partials once) ----------------
__global__ void k_h(const float* x, const float* cwp_part, float* h){
    __shared__ float cw[3072];
    int b = blockIdx.y;
    for (int j = threadIdx.x; j < 3072; j += 256){
        float s = 0.f;
        for (int ob = 0; ob < 8; ++ob) s += cwp_part[ob*3072 + j];
        cw[j] = s;
    }
    __syncthreads();
    int w = threadIdx.x >> 6, lane = threadIdx.x & 63;
    int s = blockIdx.x*4 + w;
    const float4* xr = (const float4*)(x + ((size_t)b*S_ + s)*D_);
    const float4* c0 = (const float4*)(cw);
    const float4* c1 = (const float4*)(cw + D_);
    const float4* c2 = (const float4*)(cw + 2*D_);
    float a0 = 0.f, a1 = 0.f, a2 = 0.f;
    #pragma unroll
    for (int it = 0; it < 4; ++it){
        float4 v  = xr[it*64 + lane];
        float4 w0 = c0[it*64 + lane];
        float4 w1 = c1[it*64 + lane];
        float4 w2 = c2[it*64 + lane];
        a0 += v.x*w0.x + v.y*w0.y + v.z*w0.z + v.w*w0.w;
        a1 += v.x*w1.x + v.y*w1.y + v.z*w1.z + v.w*w1.w;
        a2 += v.x*w2.x + v.y*w2.y + v.z*w2.z + v.w*w2.w;
    }
    for (int off = 32; off; off >>= 1){
        a0 += __shfl_down(a0, off);
        a1 += __shfl_down(a1, off);
        a2 += __shfl_down(a2, off);
    }
    if (lane == 0){
        h[(0*B_ + b)*S_ + s] = a0;
        h[(1*B_ + b)*S_ + s] = a1;
        h[(2*B_ + b)*S_ + s] = a2;
    }
}

// ---------------- router: xw (softmax over seq computed in-block from h) ----------------
__global__ void k_xw(const float* x, const float* h, const float* constk, float* xwl){
    int b = blockIdx.y;
    int lane = threadIdx.x & 63;
    int w = threadIdx.x >> 6;
    int i = blockIdx.x*64 + lane;
    __shared__ float red[256];
    __shared__ float wsm_l[S_];
    __shared__ float red3[3][4][64];
    const float* h0 = h + (0*B_ + b)*S_;
    const float* h1 = h + (1*B_ + b)*S_;
    const float* h2 = h + (2*B_ + b)*S_;
    float ck = *constk;
    float mx = -1e30f;
    for (int s = threadIdx.x; s < S_; s += 256){
        float v = h1[s] + ck;
        if (s >= 1)   v += h0[s-1];
        if (s+1 < S_) v += h2[s+1];
        wsm_l[s] = v;
        mx = fmaxf(mx, v);
    }
    red[threadIdx.x] = mx; __syncthreads();
    for (int st = 128; st > 0; st >>= 1){
        if (threadIdx.x < st) red[threadIdx.x] = fmaxf(red[threadIdx.x], red[threadIdx.x+st]);
        __syncthreads();
    }
    mx = red[0]; __syncthreads();
    float sum = 0.f;
    for (int s = threadIdx.x; s < S_; s += 256) sum += __expf(wsm_l[s] - mx);
    red[threadIdx.x] = sum; __syncthreads();
    for (int st = 128; st > 0; st >>= 1){
        if (threadIdx.x < st) red[threadIdx.x] += red[threadIdx.x+st];
        __syncthreads();
    }
    float inv = 1.f / red[0];
    __syncthreads();
    for (int s = threadIdx.x; s < S_; s += 256)
        wsm_l[s] = __expf(wsm_l[s] - mx) * inv;
    __syncthreads();
    const float* xb = x + (size_t)b*S_*D_;
    float a0 = 0.f, a1 = 0.f, a2 = 0.f;
    #pragma unroll 4
    for (int r = w*256; r < (w+1)*256; ++r){
        float xv = xb[(size_t)r*D_ + i];
        float w1 = wsm_l[r];
        float w0 = (r+1 < S_) ? wsm_l[r+1] : 0.f;
        float w2 = (r >= 1)   ? wsm_l[r-1] : 0.f;
        a0 += w0*xv; a1 += w1*xv; a2 += w2*xv;
    }
    red3[0][w][lane] = a0; red3[1][w][lane] = a1; red3[2][w][lane] = a2;
    __syncthreads();
    if (w == 0){
        a0 = red3[0][0][lane] + red3[0][1][lane] + red3[0][2][lane] + red3[0][3][lane];
        a1 = red3[1][0][lane] + red3[1][1][lane] + red3[1][2][lane] + red3[1][3][lane];
        a2 = red3[2][0][lane] + red3[2][1][lane] + red3[2][2][lane] + red3[2][3][lane];
        xwl[b*3072 + i*3 + 0] = a0;
        xwl[b*3072 + i*3 + 1] = a1;
        xwl[b*3072 + i*3 + 2] = a2;
    }
}

// ---------------- router: pooled[b,o] ----------------
__global__ void k_pooled(const float* conv_w, const float* conv_b, const float* xwl, float* pooled){
    int o = blockIdx.x*4 + (threadIdx.x >> 6);
    int lane = threadIdx.x & 63;
    const float* cw = conv_w + (size_t)o*3072;
    float a0=0.f, a1=0.f, a2=0.f, a3=0.f;
    for (int j = lane; j < 3072; j += 64){
        float c = cw[j];
        a0 += c*xwl[j]; a1 += c*xwl[3072+j]; a2 += c*xwl[2*3072+j]; a3 += c*xwl[3*3072+j];
    }
    for (int off = 32; off; off >>= 1){
        a0 += __shfl_down(a0, off); a1 += __shfl_down(a1, off);
        a2 += __shfl_down(a2, off); a3 += __shfl_down(a3, off);
    }
    if (lane == 0){
        float cb = conv_b[o];
        pooled[0*D_+o] = a0+cb; pooled[1*D_+o] = a1+cb;
        pooled[2*D_+o] = a2+cb; pooled[3*D_+o] = a3+cb;
    }
}

// ---------------- AeffT (route recomputed in-block; k_route launch eliminated) ----------------
__global__ void k_aeff(const float* qA, const float* kA, const float* vA, const float* oA,
                       const float* pooled, const float* rlin_w, const float* rlin_b,
                       u16* AeffT){
    __shared__ float rt[E_];
    int dc = blockIdx.x, b = blockIdx.y, p = blockIdx.z;
    // recompute route[b][:] locally (8 x D dot + softmax)
    {
        int e = threadIdx.x >> 5, part = threadIdx.x & 31;
        float acc = 0.f;
        for (int o = part; o < D_; o += 32) acc += pooled[b*D_+o] * rlin_w[e*D_+o];
        for (int off = 16; off; off >>= 1) acc += __shfl_xor(acc, off);
        if (part == 0) rt[e] = acc + rlin_b[e];
        __syncthreads();
        if (threadIdx.x == 0){
            float mx = -1e30f;
            for (int e2 = 0; e2 < E_; ++e2) mx = fmaxf(mx, rt[e2]);
            float ex[E_], sum = 0.f;
            for (int e2 = 0; e2 < E_; ++e2){ ex[e2] = expf(rt[e2]-mx); sum += ex[e2]; }
            for (int e2 = 0; e2 < E_; ++e2) rt[e2] = ex[e2]/sum;
        }
        __syncthreads();
    }
    const float* Ap = (p==0)?qA:(p==1)?kA:(p==2)?vA:oA;
    int z = p*4 + b;
    for (int idx = threadIdx.x; idx < 64*64; idx += 256){
        int dl = idx >> 6, kk = idx & 63;
        int d = dc*64 + dl;
        int e = kk >> 3, r = kk & 7;
        float v = 2.0f * rt[e] * Ap[(size_t)(e*R_+r)*D_ + d];
        AeffT[((size_t)z*D_ + d)*64 + kk] = f2b(v);
    }
}

// ---------------- Weff[z][n][d] = W_p[n,d] + Bfold[n,:] @ AeffT[:,d]  (K=64 MFMA) ----------------
__global__ __launch_bounds__(256) void k_weff(
        const u16* B16,
        const float* qW, const float* kW, const float* vW, const float* oW,
        const u16* AeffT, u16* Weff){
    __shared__ __align__(16) u16 As[128*64];
    __shared__ __align__(16) u16 Bs[128*64];
    int z = blockIdx.z, p = z >> 2;
    const u16* Bp = B16 + (size_t)p*E_*D_*R_;
    const float* Wp = (p==0)?qW:(p==1)?kW:(p==2)?vW:oW;
    int n0 = blockIdx.x*128, d0 = blockIdx.y*128;
    int tid = threadIdx.x;
    int e = tid & 7, row = tid >> 3;
    for (int pass = 0; pass < 4; ++pass){
        int rr = row + pass*32;
        GLOAD16(&Bp[((size_t)e*D_ + (n0+rr))*R_],           &As[pass*2048 + tid*8]);
        GLOAD16(&AeffT[((size_t)z*D_ + (d0+rr))*64 + e*8],  &Bs[pass*2048 + tid*8]);
    }
    __syncthreads();
    int l = tid & 63, w = tid >> 6;
    int wm = (w & 1)*64, wn = (w >> 1)*64;
    int lr = l & 15, quad = l >> 4;
    f32x4 acc[4][4] = {};
    for (int kk = 0; kk < 64; kk += 32){
        bf16x8 af[4], bg[4];
        for (int i = 0; i < 4; ++i) af[i] = *(const bf16x8*)&As[(wm + i*16 + lr)*64 + kk + quad*8];
        for (int j = 0; j < 4; ++j) bg[j] = *(const bf16x8*)&Bs[(wn + j*16 + lr)*64 + kk + quad*8];
        for (int i = 0; i < 4; ++i)
            for (int j = 0; j < 4; ++j)
                acc[i][j] = __builtin_amdgcn_mfma_f32_16x16x32_bf16(af[i], bg[j], acc[i][j], 0, 0, 0);
    }
    u16* Wz = Weff + (size_t)z*D_*D_;
    for (int i = 0; i < 4; ++i)
        for (int j = 0; j < 4; ++j)
            for (int r2 = 0; r2 < 4; ++r2){
                int n = n0 + wm + i*16 + quad*4 + r2;
                int d = d0 + wn + j*16 + lr;
                Wz[(size_t)n*D_ + d] = f2b(acc[i][j][r2] + Wp[(size_t)n*D_ + d]);
            }
}

// ---------------- fused q/k/v projection; v blocks write vT directly (LDS transpose) ----------------
__global__ __launch_bounds__(256) void k_gemm_qkv(
        const u16* x16, const u16* Weff, u16* qkv, u16* vT, const float* qb, const float* vb){
    __shared__ __align__(16) u16 As[128*32];
    __shared__ __align__(16) u16 Bs[128*32];
    __shared__ __align__(16) u16 T[64*72];     // v transpose buffer (9 KB)
    int z = blockIdx.z, p = z >> 2, b = z & 3;
    const u16* A  = x16 + (size_t)b*S_*D_;
    const u16* Bw = Weff + (size_t)z*D_*D_;
    int m0 = blockIdx.x*128, n0 = blockIdx.y*128;
    int tid = threadIdx.x;
    int srow = tid >> 2, skc = (tid & 3)*8;
    u16* asd = &As[tid*8];
    u16* bsd = &Bs[tid*8];
    const u16* ga0 = &A [(size_t)(m0+srow)*D_ + skc];
    const u16* ga1 = &A [(size_t)(m0+srow+64)*D_ + skc];
    const u16* gb0 = &Bw[(size_t)(n0+srow)*D_ + skc];
    const u16* gb1 = &Bw[(size_t)(n0+srow+64)*D_ + skc];
    int l = tid & 63, w = tid >> 6;
    int wm = (w & 1)*64, wn = (w >> 1)*64;
    int lr = l & 15, quad = l >> 4;
    f32x4 acc[4][4] = {};
    for (int k0 = 0; k0 < D_; k0 += 32){
        __syncthreads();
        GLOAD16(ga0 + k0, asd);
        GLOAD16(ga1 + k0, asd + 2048);
        GLOAD16(gb0 + k0, bsd);
        GLOAD16(gb1 + k0, bsd + 2048);
        __syncthreads();
        bf16x8 af[4], bg[4];
        for (int i = 0; i < 4; ++i) af[i] = *(const bf16x8*)&As[(wm + i*16 + lr)*32 + quad*8];
        for (int j = 0; j < 4; ++j) bg[j] = *(const bf16x8*)&Bs[(wn + j*16 + lr)*32 + quad*8];
        for (int i = 0; i < 4; ++i)
            for (int j = 0; j < 4; ++j)
                acc[i][j] = __builtin_amdgcn_mfma_f32_16x16x32_bf16(af[i], bg[j], acc[i][j], 0, 0, 0);
    }
    if (p < 2){
        const float* bias = (p==0) ? qb : (const float*)nullptr;
        const float scale = 0.35355339059327373f;   // 64^-0.25
        u16* Cb = qkv + (size_t)z*S_*D_;
        for (int j = 0; j < 4; ++j){
            int n = n0 + wn + j*16 + lr;
            float bv = bias ? bias[n] : 0.f;
            for (int i = 0; i < 4; ++i){
                int mrow = m0 + wm + i*16 + quad*4;
                for (int r2 = 0; r2 < 4; ++r2)
                    Cb[(size_t)(mrow+r2)*D_ + n] = f2b((acc[i][j][r2] + bv)*scale);
            }
        }
    } else {
        // v: write transposed into vT[bh][dh][s].  Chunk c = wave c's 64x64 tile.
        for (int c = 0; c < 4; ++c){
            if (w == c){
                for (int j = 0; j < 4; ++j){
                    int col = j*16 + lr;                       // local dh
                    float bv = vb[n0 + (c>>1)*64 + col];
                    for (int i = 0; i < 4; ++i)
                        for (int r2 = 0; r2 < 4; ++r2){
                            int row = i*16 + quad*4 + r2;      // local s
                            T[row*72 + col] = f2b(acc[i][j][r2] + bv);
                        }
                }
            }
            __syncthreads();
            int bh = b*16 + (n0 >> 6) + (c >> 1);
            int s0 = m0 + (c & 1)*64;
            int dh = tid >> 2, sp = (tid & 3)*16;
            union { u16 u[8]; uint4 q; } t0_, t1_;
            for (int jj = 0; jj < 8; ++jj){
                t0_.u[jj] = T[(sp+jj)*72 + dh];
                t1_.u[jj] = T[(sp+8+jj)*72 + dh];
            }
            *(uint4*)&vT[((size_t)bh*64 + dh)*S_ + s0 + sp]     = t0_.q;
            *(uint4*)&vT[((size_t)bh*64 + dh)*S_ + s0 + sp + 8] = t1_.q;
            __syncthreads();
        }
    }
}

// ---------------- output projection: 128x64 tiles (512 blocks = 2/CU) ----------------
__global__ __launch_bounds__(256) void k_gemm_o(
        const u16* wv, const u16* WeffO, float* out, const float* ob_){
    __shared__ __align__(16) u16 As[128*32];
    __shared__ __align__(16) u16 Bs[64*32];
    int b = blockIdx.z;
    const u16* A  = wv + (size_t)b*S_*D_;
    const u16* Bw = WeffO + (size_t)b*D_*D_;
    float* Cf = out + (size_t)b*S_*D_;
    int m0 = blockIdx.x*128, n0 = blockIdx.y*64;
    int tid = threadIdx.x;
    int srow = tid >> 2, skc = (tid & 3)*8;
    u16* asd = &As[tid*8];
    u16* bsd = &Bs[tid*8];
    const u16* ga0 = &A [(size_t)(m0+srow)*D_ + skc];
    const u16* ga1 = &A [(size_t)(m0+srow+64)*D_ + skc];
    const u16* gb0 = &Bw[(size_t)(n0+srow)*D_ + skc];
    int l = tid & 63, w = tid >> 6;
    int wm = (w & 1)*64, wn = (w >> 1)*32;
    int lr = l & 15, quad = l >> 4;
    f32x4 acc[4][2] = {};
    for (int k0 = 0; k0 < D_; k0 += 32){
        __syncthreads();
        GLOAD16(ga0 + k0, asd);
        GLOAD16(ga1 + k0, asd + 2048);
        GLOAD16(gb0 + k0, bsd);
        __syncthreads();
        bf16x8 af[4], bg[2];
        for (int i = 0; i < 4; ++i) af[i] = *(const bf16x8*)&As[(wm + i*16 + lr)*32 + quad*8];
        for (int j = 0; j < 2; ++j) bg[j] = *(const bf16x8*)&Bs[(wn + j*16 + lr)*32 + quad*8];
        for (int i = 0; i < 4; ++i)
            for (int j = 0; j < 2; ++j)
                acc[i][j] = __builtin_amdgcn_mfma_f32_16x16x32_bf16(af[i], bg[j], acc[i][j], 0, 0, 0);
    }
    for (int j = 0; j < 2; ++j){
        int n = n0 + wn + j*16 + lr;
        float bv = ob_[n];
        for (int i = 0; i < 4; ++i){
            int mrow = m0 + wm + i*16 + quad*4;
            for (int r2 = 0; r2 < 4; ++r2)
                __builtin_nontemporal_store(acc[i][j][r2] + bv, &Cf[(size_t)(mrow+r2)*D_ + n]);
        }
    }
}

// ---------------- fused attention: gload_lds + XOR-swizzled LDS (64-stride) ----------------
__global__ __launch_bounds__(256) void k_attn(const u16* q, const u16* k, const u16* vT,
                                              float* qk_out, u16* wv){
    __shared__ __align__(16) u16 Ql[64*64];
    __shared__ __align__(16) u16 Kl[64*64];
    __shared__ __align__(16) u16 Vt[64*64];
    __shared__ __align__(16) u16 Pl[64*64];
    int qt = blockIdx.x, bh = blockIdx.y;
    int b = bh >> 4, h = bh & 15;
    int q0 = qt*64;
    int tid = threadIdx.x;
    int l = tid & 63, w = tid >> 6;
    int lr = l & 15, quad = l >> 4;
    int srow = tid >> 3;
    int scol = (((tid & 7) ^ ((tid >> 3) & 7))) * 8;
    int sdst = tid * 8;
    const u16* qp  = q  + (size_t)b*S_*D_ + h*64;
    const u16* kp  = k  + (size_t)b*S_*D_ + h*64;
    const u16* vTp = vT + (size_t)bh*64*S_;
    float* qko = qk_out + (size_t)bh*S_*S_;
    GLOAD16(&qp[(size_t)(q0 + srow)*D_ + scol],      &Ql[sdst]);
    GLOAD16(&qp[(size_t)(q0 + srow + 32)*D_ + scol], &Ql[sdst + 2048]);
    int rsw = lr & 7;
    f32x4 oacc[4] = {};
    float m_i[4], l_i[4];
    for (int r2 = 0; r2 < 4; ++r2){ m_i[r2] = -1e30f; l_i[r2] = 0.f; }
    for (int t0 = 0; t0 < S_; t0 += 64){
        __syncthreads();
        GLOAD16(&kp[(size_t)(t0 + srow)*D_ + scol],        &Kl[sdst]);
        GLOAD16(&kp[(size_t)(t0 + srow + 32)*D_ + scol],   &Kl[sdst + 2048]);
        GLOAD16(&vTp[(size_t)srow*S_ + t0 + scol],         &Vt[sdst]);
        GLOAD16(&vTp[(size_t)(srow + 32)*S_ + t0 + scol],  &Vt[sdst + 2048]);
        __syncthreads();
        f32x4 sacc[4] = {};
        for (int kk = 0; kk < 64; kk += 32){
            int un = ((quad + (kk >> 3)) ^ rsw) * 8;
            bf16x8 aq = *(const bf16x8*)&Ql[(w*16 + lr)*64 + un];
            for (int jn = 0; jn < 4; ++jn){
                bf16x8 bk = *(const bf16x8*)&Kl[(jn*16 + lr)*64 + un];
                sacc[jn] = __builtin_amdgcn_mfma_f32_16x16x32_bf16(aq, bk, sacc[jn], 0, 0, 0);
            }
        }
        for (int jn = 0; jn < 4; ++jn)
            for (int r2 = 0; r2 < 4; ++r2){
                int sq = q0 + w*16 + quad*4 + r2;
                __builtin_nontemporal_store(sacc[jn][r2], &qko[(size_t)sq*S_ + t0 + jn*16 + lr]);
            }
        float alpha[4];
        for (int r2 = 0; r2 < 4; ++r2){
            float mx = fmaxf(fmaxf(sacc[0][r2], sacc[1][r2]), fmaxf(sacc[2][r2], sacc[3][r2]));
            for (int off = 1; off < 16; off <<= 1) mx = fmaxf(mx, __shfl_xor(mx, off));
            float mnew = fmaxf(m_i[r2], mx);
            alpha[r2] = __expf(m_i[r2] - mnew);
            m_i[r2] = mnew;
        }
        f32x4 p[4];
        for (int jn = 0; jn < 4; ++jn)
            for (int r2 = 0; r2 < 4; ++r2)
                p[jn][r2] = __expf(sacc[jn][r2] - m_i[r2]);
        for (int r2 = 0; r2 < 4; ++r2){
            float s = p[0][r2] + p[1][r2] + p[2][r2] + p[3][r2];
            for (int off = 1; off < 16; off <<= 1) s += __shfl_xor(s, off);
            l_i[r2] = l_i[r2]*alpha[r2] + s;
        }
        for (int jn = 0; jn < 4; ++jn)
            for (int r2 = 0; r2 < 4; ++r2)
                oacc[jn][r2] *= alpha[r2];
        for (int jn = 0; jn < 4; ++jn)
            for (int r2 = 0; r2 < 4; ++r2){
                int pr = w*16 + quad*4 + r2;
                int tu = (jn*2 + (lr >> 3)) ^ (pr & 7);
                Pl[pr*64 + tu*8 + (lr & 7)] = f2b(p[jn][r2]);
            }
        for (int kk = 0; kk < 64; kk += 32){
            int un = ((quad + (kk >> 3)) ^ rsw) * 8;
            bf16x8 ap = *(const bf16x8*)&Pl[(w*16 + lr)*64 + un];
            for (int jn = 0; jn < 4; ++jn){
                bf16x8 bv = *(const bf16x8*)&Vt[(jn*16 + lr)*64 + un];
                oacc[jn] = __builtin_amdgcn_mfma_f32_16x16x32_bf16(ap, bv, oacc[jn], 0, 0, 0);
            }
        }
    }
    u16* wvp = wv + (size_t)b*S_*D_ + h*64;
    for (int r2 = 0; r2 < 4; ++r2){
        float inv = 1.f / l_i[r2];
        int sq = q0 + w*16 + quad*4 + r2;
        for (int jn = 0; jn < 4; ++jn)
            wvp[(size_t)sq*D_ + jn*16 + lr] = f2b(oacc[jn][r2] * inv);
    }
}

extern "C" void kernel_launch(void* const* d_in, const int* in_sizes, int n_in,
                              void* d_out, int out_size, void* d_ws, size_t ws_size,
                              hipStream_t stream){
    const float* x      = (const float*)d_in[0];
    const float* conv_w = (const float*)d_in[1];
    const float* conv_b = (const float*)d_in[2];
    const float* pool_w = (const float*)d_in[3];
    const float* pool_b = (const float*)d_in[4];
    const float* rlin_w = (const float*)d_in[5];
    const float* rlin_b = (const float*)d_in[6];
    const float* qW = (const float*)d_in[7];
    const float* qb = (const float*)d_in[8];
    const float* qA = (const float*)d_in[9];
    const float* qB = (const float*)d_in[10];
    const float* kW = (const float*)d_in[11];
    const float* kA = (const float*)d_in[12];
    const float* kB = (const float*)d_in[13];
    const float* vW = (const float*)d_in[14];
    const float* vb = (const float*)d_in[15];
    const float* vA = (const float*)d_in[16];
    const float* vB = (const float*)d_in[17];
    const float* oW = (const float*)d_in[18];
    const float* ob = (const float*)d_in[19];
    const float* oA = (const float*)d_in[20];
    const float* oB = (const float*)d_in[21];

    char* ws = (char*)d_ws;
    float* constk   = (float*)(ws + 512);
    float* cwp_part = (float*)(ws + 1024);      // 96 KB
    float* h        = (float*)(ws + 131072);    // 48 KB
    float* xwl      = (float*)(ws + 196608);    // 48 KB
    float* pooled   = (float*)(ws + 262144);    // 16 KB
    u16* AeffT = (u16*)(ws + (1ull  << 20));    // 2 MB
    u16* B16   = (u16*)(ws + (3ull  << 20));    // 512 KB
    u16* Weff  = (u16*)(ws + (4ull  << 20));    // 32 MB
    u16* x16   = (u16*)(ws + (36ull << 20));    // 8 MB
    u16* qkv   = (u16*)(ws + (44ull << 20));    // 24 MB: [p][b][S][D]
    u16* qbuf  = qkv + 0*(size_t)B_*S_*D_;
    u16* kbuf  = qkv + 1*(size_t)B_*S_*D_;
    u16* vbuf  = qkv + 2*(size_t)B_*S_*D_;      // unused as v; reused as wv
    u16* vTbuf = (u16*)(ws + (68ull << 20));    // 8 MB
    u16* wvbuf = vbuf;

    float* out    = (float*)d_out;
    float* qk_out = out + (size_t)B_*S_*D_;

    const long long sDD = (long long)D_*D_;

    // 1: converts + cwp partials + constk
    k_pre<<<2145, 256, 0, stream>>>((const float4*)x, qB, kB, vB, oB,
                                    conv_w, conv_b, pool_w, pool_b,
                                    (ushort4*)x16, (ushort4*)B16, cwp_part, constk);
    // 2-5: router chain
    k_h     <<<dim3(S_/4, B_), 256, 0, stream>>>(x, cwp_part, h);
    k_xw    <<<dim3(16, B_), 256, 0, stream>>>(x, h, constk, xwl);
    k_pooled<<<256, 256, 0, stream>>>(conv_w, conv_b, xwl, pooled);
    k_aeff  <<<dim3(16, B_, 4), 256, 0, stream>>>(qA, kA, vA, oA, pooled, rlin_w, rlin_b, AeffT);
    // 6: effective weights
    k_weff  <<<dim3(8, 8, 16), 256, 0, stream>>>(B16, qW, kW, vW, oW, AeffT, Weff);
    // 7: q/k/v projections (v written transposed; 768 blocks = 3/CU)
    k_gemm_qkv<<<dim3(8,8,12), 256, 0, stream>>>(x16, Weff, qkv, vTbuf, qb, vb);
    // 8: attention
    k_attn  <<<dim3(16, B_*H_), 256, 0, stream>>>(qbuf, kbuf, vTbuf, qk_out, wvbuf);
    // 9: output projection (512 blocks = 2/CU)
    k_gemm_o<<<dim3(8,16,B_), 256, 0, stream>>>(wvbuf, Weff + 12*sDD, out, ob);
}